// Round 3
// baseline (158.408 us; speedup 1.0000x reference)
//
#include <hip/hip_runtime.h>

namespace {

constexpr int Bb   = 4;
constexpr int Nn   = 8192;
constexpr int Mm   = 8192;
constexpr int KNB  = 6;
constexpr int TILE = 256;
constexpr int MCHUNKS = 16;

__device__ inline unsigned long long shflx64(unsigned long long v, int m) {
    unsigned lo = (unsigned)v, hi = (unsigned)(v >> 32);
    lo = (unsigned)__shfl_xor((int)lo, m, 64);
    hi = (unsigned)__shfl_xor((int)hi, m, 64);
    return ((unsigned long long)hi << 32) | lo;
}

// ---------------- init: mins -> +inf, accumulators -> 0 ----------------
__global__ void init_ws_kernel(unsigned* __restrict__ minArr, float* __restrict__ acc) {
    int i = blockIdx.x * blockDim.x + threadIdx.x;
    if (i < 2 * Bb * Nn) minArr[i] = 0x7f800000u;  // +inf bits
    if (i < 8) acc[i] = 0.0f;
}

// ---------------- chamfer directional min, 2 queries/thread ----------------
// MODE 0: query = template+disp (pred_pos), db = target_pos
// MODE 1: query = target_pos,               db = template+disp
// Inner form matches reference's xx + yy - 2xy:  d2 = q2 + 2*(h - q.p), h=|p|^2/2
template <int MODE>
__global__ __launch_bounds__(256) void chamfer_min_kernel(
    const float* __restrict__ disp, const float* __restrict__ tmpl,
    const float* __restrict__ targ, unsigned* __restrict__ outMin) {
    __shared__ float4 sp[TILE];
    const int tid = threadIdx.x;
    const int b = blockIdx.z;
    const int n0 = blockIdx.x * 256 + tid;
    const int n1 = n0 + Nn / 2;
    const int mBase = blockIdx.y * (Mm / MCHUNKS);

    float q0x, q0y, q0z, q1x, q1y, q1z;
    {
        const long qb0 = (long)b * Nn * 3 + (long)n0 * 3;
        const long qb1 = (long)b * Nn * 3 + (long)n1 * 3;
        if (MODE == 0) {
            q0x = tmpl[qb0 + 0] + disp[qb0 + 0];
            q0y = tmpl[qb0 + 1] + disp[qb0 + 1];
            q0z = tmpl[qb0 + 2] + disp[qb0 + 2];
            q1x = tmpl[qb1 + 0] + disp[qb1 + 0];
            q1y = tmpl[qb1 + 1] + disp[qb1 + 1];
            q1z = tmpl[qb1 + 2] + disp[qb1 + 2];
        } else {
            q0x = targ[qb0 + 0]; q0y = targ[qb0 + 1]; q0z = targ[qb0 + 2];
            q1x = targ[qb1 + 0]; q1y = targ[qb1 + 1]; q1z = targ[qb1 + 2];
        }
    }
    const float q0sq = q0x * q0x + q0y * q0y + q0z * q0z;
    const float q1sq = q1x * q1x + q1y * q1y + q1z * q1z;
    const float a0x = -q0x, a0y = -q0y, a0z = -q0z;
    const float a1x = -q1x, a1y = -q1y, a1z = -q1z;

    float m0a = 1e38f, m1a = 1e38f;   // query 0, 2-deep
    float m0b = 1e38f, m1b = 1e38f;   // query 1, 2-deep

    for (int t0 = 0; t0 < Mm / MCHUNKS; t0 += TILE) {
        __syncthreads();
        {
            const long db = (long)b * Mm * 3 + (long)(mBase + t0 + tid) * 3;
            float x, y, z;
            if (MODE == 0) {
                x = targ[db + 0]; y = targ[db + 1]; z = targ[db + 2];
            } else {
                x = tmpl[db + 0] + disp[db + 0];
                y = tmpl[db + 1] + disp[db + 1];
                z = tmpl[db + 2] + disp[db + 2];
            }
            sp[tid] = make_float4(x, y, z, 0.5f * (x * x + y * y + z * z));
        }
        __syncthreads();

        #pragma unroll 8
        for (int j = 0; j < TILE; j += 2) {
            float4 p0 = sp[j + 0];
            float4 p1 = sp[j + 1];
            float s;
            s = fmaf(p0.x, a0x, fmaf(p0.y, a0y, fmaf(p0.z, a0z, p0.w))); m0a = fminf(m0a, s);
            s = fmaf(p0.x, a1x, fmaf(p0.y, a1y, fmaf(p0.z, a1z, p0.w))); m0b = fminf(m0b, s);
            s = fmaf(p1.x, a0x, fmaf(p1.y, a0y, fmaf(p1.z, a0z, p1.w))); m1a = fminf(m1a, s);
            s = fmaf(p1.x, a1x, fmaf(p1.y, a1y, fmaf(p1.z, a1z, p1.w))); m1b = fminf(m1b, s);
        }
    }

    float d2a = fmaf(2.0f, fminf(m0a, m1a), q0sq);
    float d2b = fmaf(2.0f, fminf(m0b, m1b), q1sq);
    atomicMin(&outMin[(long)b * Nn + n0], __float_as_uint(d2a));
    atomicMin(&outMin[(long)b * Nn + n1], __float_as_uint(d2b));
}

// ---------------- KNN on template[0] + smoothness reg (wave-per-query) ----------------
__global__ __launch_bounds__(256) void knn_smooth_kernel(
    const float* __restrict__ tmpl, const float* __restrict__ disp,
    float* __restrict__ acc) {
    const int lane = threadIdx.x & 63;
    const int wid  = threadIdx.x >> 6;
    const int q    = blockIdx.x * 4 + wid;

    const float qx = tmpl[q * 3 + 0];
    const float qy = tmpl[q * 3 + 1];
    const float qz = tmpl[q * 3 + 2];

    const unsigned long long MAXK = ~0ULL;
    unsigned long long l0 = MAXK, l1 = MAXK, l2 = MAXK, l3 = MAXK,
                       l4 = MAXK, l5 = MAXK, l6 = MAXK;

    // each lane scans 128 points, strided for coalescing; key=(d2bits<<32)|idx
    for (int i = 0; i < Nn / 64; ++i) {
        const int p = i * 64 + lane;
        const float px = tmpl[p * 3 + 0];
        const float py = tmpl[p * 3 + 1];
        const float pz = tmpl[p * 3 + 2];
        const float dx = qx - px, dy = qy - py, dz = qz - pz;
        const float d2 = dx * dx + dy * dy + dz * dz;
        unsigned long long key =
            ((unsigned long long)__float_as_uint(d2) << 32) | (unsigned)p;
        if (key < l6) {
            l6 = key;
            if (l6 < l5) { auto t = l5; l5 = l6; l6 = t; }
            if (l5 < l4) { auto t = l4; l4 = l5; l5 = t; }
            if (l4 < l3) { auto t = l3; l3 = l4; l4 = t; }
            if (l3 < l2) { auto t = l2; l2 = l3; l3 = t; }
            if (l2 < l1) { auto t = l1; l1 = l2; l2 = t; }
            if (l1 < l0) { auto t = l0; l0 = l1; l1 = t; }
        }
    }

    // 7-round tournament: global 7 smallest keys across the wave.
    // best[0] is self (d2==0, lowest idx on ties — matches top_k stability).
    unsigned long long best[7];
    #pragma unroll
    for (int t = 0; t < 7; ++t) {
        unsigned long long h = l0;
        #pragma unroll
        for (int off = 32; off; off >>= 1) {
            unsigned long long o = shflx64(h, off);
            h = (o < h) ? o : h;
        }
        best[t] = h;
        const bool pop = (l0 == h);
        l0 = pop ? l1 : l0; l1 = pop ? l2 : l1; l2 = pop ? l3 : l2;
        l3 = pop ? l4 : l3; l4 = pop ? l5 : l4; l5 = pop ? l6 : l5;
        l6 = pop ? MAXK : l6;
    }

    // smoothness: lanes 0..23 -> (neighbor k=1..6, batch b=0..3)
    float s = 0.0f;
    if (lane < 24) {
        const int kk = lane >> 2;   // 0..5
        const int b  = lane & 3;
        int j = (int)(unsigned)best[1];
        if (kk == 1) j = (int)(unsigned)best[2];
        if (kk == 2) j = (int)(unsigned)best[3];
        if (kk == 3) j = (int)(unsigned)best[4];
        if (kk == 4) j = (int)(unsigned)best[5];
        if (kk == 5) j = (int)(unsigned)best[6];
        const float* dn = disp + ((long)b * Nn + q) * 3;
        const float* dj = disp + ((long)b * Nn + j) * 3;
        const float ddx = dj[0] - dn[0];
        const float ddy = dj[1] - dn[1];
        const float ddz = dj[2] - dn[2];
        s = ddx * ddx + ddy * ddy + ddz * ddz;
    }
    #pragma unroll
    for (int off = 32; off; off >>= 1) s += __shfl_xor(s, off, 64);

    __shared__ float wsum[4];
    if (lane == 0) wsum[wid] = s;
    __syncthreads();
    if (threadIdx.x == 0)
        atomicAdd(&acc[3], wsum[0] + wsum[1] + wsum[2] + wsum[3]);
}

// ---- fused tail: sqrt-of-mins sum + mat loss + disp reg ----
__global__ __launch_bounds__(256) void tail_reduce_kernel(
    const float* __restrict__ minArr, const float* __restrict__ pm,
    const float* __restrict__ tm, const float* __restrict__ dp,
    float* __restrict__ acc) {
    const int tid = threadIdx.x;
    const int stride = gridDim.x * blockDim.x;
    float sc = 0.0f, sm = 0.0f, sd = 0.0f;
    for (int i = blockIdx.x * blockDim.x + tid; i < 2 * Bb * Nn; i += stride) {
        sc += sqrtf(fmaxf(minArr[i], 1e-12f));
    }
    for (int i = blockIdx.x * blockDim.x + tid; i < Bb * Nn * 4; i += stride) {
        float d = pm[i] - tm[i];
        sm += d * d;
    }
    for (int i = blockIdx.x * blockDim.x + tid; i < Bb * Nn * 3; i += stride) {
        float v = dp[i];
        sd += v * v;
    }
    __shared__ float r0[256], r1[256], r2[256];
    r0[tid] = sc; r1[tid] = sm; r2[tid] = sd;
    __syncthreads();
    for (int w = 128; w > 0; w >>= 1) {
        if (tid < w) { r0[tid] += r0[tid + w]; r1[tid] += r1[tid + w]; r2[tid] += r2[tid + w]; }
        __syncthreads();
    }
    if (tid == 0) {
        atomicAdd(&acc[0], r0[0]);
        atomicAdd(&acc[1], r1[0]);
        atomicAdd(&acc[2], r2[0]);
    }
}

// ---------------- finalize ----------------
__global__ void finalize_kernel(const float* __restrict__ acc, float* __restrict__ out) {
    if (threadIdx.x == 0 && blockIdx.x == 0) {
        float cd  = acc[0] / (2.0f * Bb * Nn);            // (sum_p2t + sum_t2p)/(2*B*N), N==M
        float mat = acc[1] / (float)(Bb * Nn * 4);
        float dr  = acc[2] / (float)(Bb * Nn * 3);
        float sm  = acc[3] / (float)(Bb * Nn * KNB * 3);
        out[0] = 1.0f * cd + 0.1f * mat + 0.01f * dr + 0.005f * sm;
    }
}

}  // namespace

extern "C" void kernel_launch(void* const* d_in, const int* in_sizes, int n_in,
                              void* d_out, int out_size, void* d_ws, size_t ws_size,
                              hipStream_t stream) {
    const float* pred_disp  = (const float*)d_in[0];
    const float* pred_mat   = (const float*)d_in[1];
    const float* target_pos = (const float*)d_in[2];
    const float* target_mat = (const float*)d_in[3];
    const float* tmpl       = (const float*)d_in[4];

    float* ws = (float*)d_ws;
    unsigned* minP = (unsigned*)ws;           // B*N entries (pred->target d2 mins)
    unsigned* minT = minP + Bb * Nn;          // B*M entries (target->pred d2 mins)
    float* acc = ws + 2 * Bb * Nn;            // 8 accumulators

    init_ws_kernel<<<(2 * Bb * Nn) / 256, 256, 0, stream>>>(minP, acc);

    dim3 cgrid(Nn / 512, MCHUNKS, Bb);        // 2 queries per thread
    chamfer_min_kernel<0><<<cgrid, 256, 0, stream>>>(pred_disp, tmpl, target_pos, minP);
    chamfer_min_kernel<1><<<cgrid, 256, 0, stream>>>(pred_disp, tmpl, target_pos, minT);

    knn_smooth_kernel<<<Nn / 4, 256, 0, stream>>>(tmpl, pred_disp, acc);  // FIXED grid

    tail_reduce_kernel<<<64, 256, 0, stream>>>((const float*)minP, pred_mat, target_mat,
                                               pred_disp, acc);

    finalize_kernel<<<1, 64, 0, stream>>>(acc, (float*)d_out);
}

// Round 4
// 127.130 us; speedup vs baseline: 1.2460x; 1.2460x over previous
//
#include <hip/hip_runtime.h>

namespace {

constexpr int Bb = 4, Nn = 8192, Mm = 8192, KNB = 6;
constexpr int CH_TILE = 256, MCHUNKS = 32, QPT = 8;   // chamfer
constexpr int KJ = 64, KCH = 32, KCPTS = 256;         // knn: slab height, chunks, pts/chunk

__device__ inline unsigned ordkey(float f) {
    unsigned b = __float_as_uint(f);
    return b ^ (unsigned)(((int)b >> 31) | 0x80000000);
}
__device__ inline float invordkey(unsigned u) {
    unsigned b = (u & 0x80000000u) ? (u ^ 0x80000000u) : ~u;
    return __uint_as_float(b);
}
__device__ inline unsigned long long shflx64(unsigned long long v, int m) {
    unsigned lo = (unsigned)v, hi = (unsigned)(v >> 32);
    lo = (unsigned)__shfl_xor((int)lo, m, 64);
    hi = (unsigned)__shfl_xor((int)hi, m, 64);
    return ((unsigned long long)hi << 32) | lo;
}

// ---------------- init: mins -> +inf, accumulators -> 0 ----------------
__global__ void init_ws_kernel(unsigned* __restrict__ minArr, float* __restrict__ acc) {
    int i = blockIdx.x * blockDim.x + threadIdx.x;
    if (i < 2 * Bb * Nn) minArr[i] = 0x7f800000u;  // +inf bits
    if (i < 8) acc[i] = 0.0f;
}

// ---------------- chamfer: both directions, 8 queries/thread ----------------
// dir 0: query = template+disp, db = target ; dir 1: query = target, db = template+disp
// s = h - q.p (h = |p|^2/2), d2 = 2*min(s) + |q|^2  == xx + yy - 2xy form
__global__ __launch_bounds__(256) void chamfer_min_kernel(
    const float* __restrict__ disp, const float* __restrict__ tmpl,
    const float* __restrict__ targ, unsigned* __restrict__ outMin) {
    __shared__ float4 sp[CH_TILE];
    const int tid = threadIdx.x;
    const int dir = blockIdx.z & 1;
    const int b = blockIdx.z >> 1;
    const int mBase = blockIdx.y * CH_TILE;

    float ax[QPT], ay[QPT], az[QPT], qs[QPT], mn[QPT];
    #pragma unroll
    for (int k = 0; k < QPT; ++k) {
        const int n = blockIdx.x * 256 + tid + k * (Nn / QPT);
        const long e = ((long)b * Nn + n) * 3;
        float x, y, z;
        if (dir == 0) {
            x = tmpl[e] + disp[e]; y = tmpl[e+1] + disp[e+1]; z = tmpl[e+2] + disp[e+2];
        } else {
            x = targ[e]; y = targ[e+1]; z = targ[e+2];
        }
        ax[k] = -x; ay[k] = -y; az[k] = -z;
        qs[k] = x*x + y*y + z*z;
        mn[k] = 1e38f;
    }
    {
        const long e = ((long)b * Mm + mBase + tid) * 3;
        float x, y, z;
        if (dir == 0) {
            x = targ[e]; y = targ[e+1]; z = targ[e+2];
        } else {
            x = tmpl[e] + disp[e]; y = tmpl[e+1] + disp[e+1]; z = tmpl[e+2] + disp[e+2];
        }
        sp[tid] = make_float4(x, y, z, 0.5f * (x*x + y*y + z*z));
    }
    __syncthreads();

    #pragma unroll 4
    for (int j = 0; j < CH_TILE; ++j) {
        const float4 P = sp[j];
        #pragma unroll
        for (int k = 0; k < QPT; ++k) {
            const float s = fmaf(P.x, ax[k], fmaf(P.y, ay[k], fmaf(P.z, az[k], P.w)));
            mn[k] = fminf(mn[k], s);
        }
    }

    #pragma unroll
    for (int k = 0; k < QPT; ++k) {
        const int n = blockIdx.x * 256 + tid + k * (Nn / QPT);
        const float d2 = fmaf(2.0f, mn[k], qs[k]);
        atomicMin(&outMin[((long)dir * Bb + b) * Nn + n], __float_as_uint(d2));
    }
}

// ---------------- KNN: 2 queries x 32 chunk-lanes per wave, two-phase ----------------
__global__ __launch_bounds__(256) void knn_smooth_kernel(
    const float* __restrict__ tmpl, const float* __restrict__ disp,
    float* __restrict__ acc) {
    __shared__ float4 tile[KJ * KCH];   // 32 KB, point-major, XOR-swizzled
    __shared__ float wsum[4];
    const int tid = threadIdx.x;
    const int lane = tid & 63;
    const int wid = tid >> 6;
    const int c = lane & 31;                       // chunk this lane owns
    const int q = blockIdx.x * 8 + (wid << 1) + (lane >> 5);

    const float qx = tmpl[q*3+0], qy = tmpl[q*3+1], qz = tmpl[q*3+2];
    const float ax = -qx, ay = -qy, az = -qz;
    const float INFf = __uint_as_float(0x7f800000u);

    // ---- phase A: chunk-min of s over this lane's 256 points ----
    float cmin = INFf;
    for (int slab = 0; slab < KCPTS / KJ; ++slab) {
        const int j0 = slab * KJ;
        __syncthreads();
        #pragma unroll
        for (int k = 0; k < (KJ * KCH) / 256; ++k) {
            const int pl = k * 256 + tid;
            const int cc = pl >> 6;                // KJ == 64
            const int jj = pl & (KJ - 1);
            const int p = cc * KCPTS + j0 + jj;
            const float x = tmpl[p*3+0], y = tmpl[p*3+1], z = tmpl[p*3+2];
            tile[jj * KCH + (cc ^ (jj & 31))] =
                make_float4(x, y, z, 0.5f * (x*x + y*y + z*z));
        }
        __syncthreads();
        #pragma unroll 4
        for (int jj = 0; jj < KJ; ++jj) {
            const float4 P = tile[jj * KCH + (c ^ (jj & 31))];
            const float s = fmaf(P.x, ax, fmaf(P.y, ay, fmaf(P.z, az, P.w)));
            cmin = fminf(cmin, s);
        }
    }

    // ---- T = 7th smallest of the 32 chunk-mins (knockout tournament, per half) ----
    float v = cmin, T = cmin;
    #pragma unroll
    for (int t = 0; t < 7; ++t) {
        float h = v;
        h = fminf(h, __shfl_xor(h, 16, 64));
        h = fminf(h, __shfl_xor(h, 8, 64));
        h = fminf(h, __shfl_xor(h, 4, 64));
        h = fminf(h, __shfl_xor(h, 2, 64));
        h = fminf(h, __shfl_xor(h, 1, 64));
        T = h;
        if (v == h) v = INFf;   // knock out achieving lane(s); bound stays valid
    }

    // ---- phase B: sentinel-initialized exact top-7, inserts now rare ----
    const unsigned long long sent =
        ((unsigned long long)ordkey(T) << 32) | 0xFFFFFFFFull;
    unsigned long long l0=sent,l1=sent,l2=sent,l3=sent,l4=sent,l5=sent,l6=sent;
    float cur7 = T;

    for (int slab = 0; slab < KCPTS / KJ; ++slab) {
        const int j0 = slab * KJ;
        __syncthreads();
        #pragma unroll
        for (int k = 0; k < (KJ * KCH) / 256; ++k) {
            const int pl = k * 256 + tid;
            const int cc = pl >> 6;
            const int jj = pl & (KJ - 1);
            const int p = cc * KCPTS + j0 + jj;
            const float x = tmpl[p*3+0], y = tmpl[p*3+1], z = tmpl[p*3+2];
            tile[jj * KCH + (cc ^ (jj & 31))] =
                make_float4(x, y, z, 0.5f * (x*x + y*y + z*z));
        }
        __syncthreads();
        #pragma unroll 2
        for (int jj = 0; jj < KJ; ++jj) {
            const float4 P = tile[jj * KCH + (c ^ (jj & 31))];
            const float s = fmaf(P.x, ax, fmaf(P.y, ay, fmaf(P.z, az, P.w)));
            if (s <= cur7) {
                const int p = c * KCPTS + j0 + jj;
                const unsigned long long key =
                    ((unsigned long long)ordkey(s) << 32) | (unsigned)p;
                if (key < l6) {
                    l6 = key;
                    if (l6 < l5) { auto t = l5; l5 = l6; l6 = t; }
                    if (l5 < l4) { auto t = l4; l4 = l5; l5 = t; }
                    if (l4 < l3) { auto t = l3; l3 = l4; l4 = t; }
                    if (l3 < l2) { auto t = l2; l2 = l3; l3 = t; }
                    if (l2 < l1) { auto t = l1; l1 = l2; l2 = t; }
                    if (l1 < l0) { auto t = l0; l0 = l1; l1 = t; }
                    cur7 = invordkey((unsigned)(l6 >> 32));
                }
            }
        }
    }

    // ---- merge: 7-round tournament across the 32 chunk-lanes (per half) ----
    unsigned long long best[7];
    #pragma unroll
    for (int t = 0; t < 7; ++t) {
        unsigned long long h = l0;
        h = (shflx64(h, 16) < h) ? shflx64(h, 16) : h;
        {
            unsigned long long o;
            o = shflx64(h, 8); h = (o < h) ? o : h;
            o = shflx64(h, 4); h = (o < h) ? o : h;
            o = shflx64(h, 2); h = (o < h) ? o : h;
            o = shflx64(h, 1); h = (o < h) ? o : h;
        }
        best[t] = h;
        const bool pop = (l0 == h);
        l0 = pop ? l1 : l0; l1 = pop ? l2 : l1; l2 = pop ? l3 : l2;
        l3 = pop ? l4 : l3; l4 = pop ? l5 : l4; l5 = pop ? l6 : l5;
        l6 = pop ? ~0ULL : l6;
    }

    // best[0] = self (d2=0 minimal, idx tie-break); neighbors best[1..6]
    float s = 0.0f;
    const int l32 = lane & 31;
    if (l32 < 24) {
        const int kk = l32 >> 2;   // neighbor 0..5
        const int bb = l32 & 3;    // batch
        int j = (int)(unsigned)best[1];
        if (kk == 1) j = (int)(unsigned)best[2];
        if (kk == 2) j = (int)(unsigned)best[3];
        if (kk == 3) j = (int)(unsigned)best[4];
        if (kk == 4) j = (int)(unsigned)best[5];
        if (kk == 5) j = (int)(unsigned)best[6];
        const float* dn = disp + ((long)bb * Nn + q) * 3;
        const float* dj = disp + ((long)bb * Nn + j) * 3;
        const float ddx = dj[0] - dn[0];
        const float ddy = dj[1] - dn[1];
        const float ddz = dj[2] - dn[2];
        s = ddx*ddx + ddy*ddy + ddz*ddz;
    }
    #pragma unroll
    for (int off = 32; off; off >>= 1) s += __shfl_xor(s, off, 64);

    if (lane == 0) wsum[wid] = s;
    __syncthreads();
    if (tid == 0)
        atomicAdd(&acc[3], wsum[0] + wsum[1] + wsum[2] + wsum[3]);
}

// ---- fused tail: sqrt-of-mins sum + mat loss + disp reg ----
__global__ __launch_bounds__(256) void tail_reduce_kernel(
    const float* __restrict__ minArr, const float* __restrict__ pm,
    const float* __restrict__ tm, const float* __restrict__ dp,
    float* __restrict__ acc) {
    const int tid = threadIdx.x;
    const int stride = gridDim.x * blockDim.x;
    float sc = 0.0f, sm = 0.0f, sd = 0.0f;
    for (int i = blockIdx.x * blockDim.x + tid; i < 2 * Bb * Nn; i += stride) {
        sc += sqrtf(fmaxf(minArr[i], 1e-12f));
    }
    for (int i = blockIdx.x * blockDim.x + tid; i < Bb * Nn * 4; i += stride) {
        float d = pm[i] - tm[i];
        sm += d * d;
    }
    for (int i = blockIdx.x * blockDim.x + tid; i < Bb * Nn * 3; i += stride) {
        float v = dp[i];
        sd += v * v;
    }
    __shared__ float r0[256], r1[256], r2[256];
    r0[tid] = sc; r1[tid] = sm; r2[tid] = sd;
    __syncthreads();
    for (int w = 128; w > 0; w >>= 1) {
        if (tid < w) { r0[tid] += r0[tid + w]; r1[tid] += r1[tid + w]; r2[tid] += r2[tid + w]; }
        __syncthreads();
    }
    if (tid == 0) {
        atomicAdd(&acc[0], r0[0]);
        atomicAdd(&acc[1], r1[0]);
        atomicAdd(&acc[2], r2[0]);
    }
}

// ---------------- finalize ----------------
__global__ void finalize_kernel(const float* __restrict__ acc, float* __restrict__ out) {
    if (threadIdx.x == 0 && blockIdx.x == 0) {
        float cd  = acc[0] / (2.0f * Bb * Nn);
        float mat = acc[1] / (float)(Bb * Nn * 4);
        float dr  = acc[2] / (float)(Bb * Nn * 3);
        float sm  = acc[3] / (float)(Bb * Nn * KNB * 3);
        out[0] = 1.0f * cd + 0.1f * mat + 0.01f * dr + 0.005f * sm;
    }
}

}  // namespace

extern "C" void kernel_launch(void* const* d_in, const int* in_sizes, int n_in,
                              void* d_out, int out_size, void* d_ws, size_t ws_size,
                              hipStream_t stream) {
    const float* pred_disp  = (const float*)d_in[0];
    const float* pred_mat   = (const float*)d_in[1];
    const float* target_pos = (const float*)d_in[2];
    const float* target_mat = (const float*)d_in[3];
    const float* tmpl       = (const float*)d_in[4];

    float* ws = (float*)d_ws;
    unsigned* minArr = (unsigned*)ws;         // 2*B*N: [dir0: pred->targ][dir1: targ->pred]
    float* acc = ws + 2 * Bb * Nn;            // 8 accumulators

    init_ws_kernel<<<(2 * Bb * Nn) / 256, 256, 0, stream>>>(minArr, acc);

    dim3 cgrid(Nn / 256 / QPT, MCHUNKS, Bb * 2);   // (4, 32, 8)
    chamfer_min_kernel<<<cgrid, 256, 0, stream>>>(pred_disp, tmpl, target_pos, minArr);

    knn_smooth_kernel<<<Nn / 8, 256, 0, stream>>>(tmpl, pred_disp, acc);

    tail_reduce_kernel<<<128, 256, 0, stream>>>((const float*)minArr, pred_mat, target_mat,
                                                pred_disp, acc);

    finalize_kernel<<<1, 64, 0, stream>>>(acc, (float*)d_out);
}

// Round 5
// 104.584 us; speedup vs baseline: 1.5146x; 1.2156x over previous
//
#include <hip/hip_runtime.h>

namespace {

constexpr int Bb = 4, Nn = 8192, Mm = 8192, KNB = 6;
constexpr int CH_TILE = 256, MCHUNKS = 32, QPT = 16;  // chamfer
constexpr int KSLAB = 2048;                           // knn slab (points), 32KB
constexpr int KCAP = 96;                              // knn candidate slots per query

__device__ inline unsigned ordkey(float f) {
    unsigned b = __float_as_uint(f);
    return b ^ (unsigned)(((int)b >> 31) | 0x80000000);
}

// ---------------- init: mins -> +inf, accumulators -> 0 ----------------
__global__ void init_ws_kernel(unsigned* __restrict__ minArr, float* __restrict__ acc) {
    int i = blockIdx.x * blockDim.x + threadIdx.x;
    if (i < 2 * Bb * Nn) minArr[i] = 0x7f800000u;  // +inf bits
    if (i < 8) acc[i] = 0.0f;
}

// ---------------- chamfer: both directions, 16 queries/thread ----------------
// dir 0: query = template+disp, db = target ; dir 1: query = target, db = template+disp
// s = h - q.p (h = |p|^2/2), d2 = 2*min(s) + |q|^2  == xx + yy - 2xy form
__global__ __launch_bounds__(256) void chamfer_min_kernel(
    const float* __restrict__ disp, const float* __restrict__ tmpl,
    const float* __restrict__ targ, unsigned* __restrict__ outMin) {
    __shared__ float4 sp[CH_TILE];
    const int tid = threadIdx.x;
    const int dir = blockIdx.z & 1;
    const int b = blockIdx.z >> 1;
    const int mBase = blockIdx.y * CH_TILE;

    float ax[QPT], ay[QPT], az[QPT], qs[QPT], mn[QPT];
    #pragma unroll
    for (int k = 0; k < QPT; ++k) {
        const int n = blockIdx.x * 256 + tid + k * (Nn / QPT);
        const long e = ((long)b * Nn + n) * 3;
        float x, y, z;
        if (dir == 0) {
            x = tmpl[e] + disp[e]; y = tmpl[e+1] + disp[e+1]; z = tmpl[e+2] + disp[e+2];
        } else {
            x = targ[e]; y = targ[e+1]; z = targ[e+2];
        }
        ax[k] = -x; ay[k] = -y; az[k] = -z;
        qs[k] = x*x + y*y + z*z;
        mn[k] = 1e38f;
    }
    {
        const long e = ((long)b * Mm + mBase + tid) * 3;
        float x, y, z;
        if (dir == 0) {
            x = targ[e]; y = targ[e+1]; z = targ[e+2];
        } else {
            x = tmpl[e] + disp[e]; y = tmpl[e+1] + disp[e+1]; z = tmpl[e+2] + disp[e+2];
        }
        sp[tid] = make_float4(x, y, z, 0.5f * (x*x + y*y + z*z));
    }
    __syncthreads();

    #pragma unroll 4
    for (int j = 0; j < CH_TILE; ++j) {
        const float4 P = sp[j];
        #pragma unroll
        for (int k = 0; k < QPT; ++k) {
            const float s = fmaf(P.x, ax[k], fmaf(P.y, ay[k], fmaf(P.z, az[k], P.w)));
            mn[k] = fminf(mn[k], s);
        }
    }

    #pragma unroll
    for (int k = 0; k < QPT; ++k) {
        const int n = blockIdx.x * 256 + tid + k * (Nn / QPT);
        const float d2 = fmaf(2.0f, mn[k], qs[k]);
        atomicMin(&outMin[((long)dir * Bb + b) * Nn + n], __float_as_uint(d2));
    }
}

// ---------------- KNN: wave = 4 queries x 64 lane-chunks; candidate-buffer phase B ----
__global__ __launch_bounds__(256) void knn_smooth_kernel(
    const float* __restrict__ tmpl, const float* __restrict__ disp,
    float* __restrict__ acc) {
    __shared__ float4 sp4[KSLAB];                        // 32 KB, point-major
    __shared__ unsigned long long cand[16][KCAP];        // 12 KB
    __shared__ int cnt[16];

    const int tid = threadIdx.x;
    const int lane = tid & 63;
    const int wid = tid >> 6;           // wave 0..3
    const int c = lane;                 // chunk = stride-64 interleave class

    const int qbase = blockIdx.x * 16 + wid * 4;
    float qx[4], qy[4], qz[4], axq[4], ayq[4], azq[4];
    #pragma unroll
    for (int i = 0; i < 4; ++i) {
        qx[i] = tmpl[(qbase + i) * 3 + 0];
        qy[i] = tmpl[(qbase + i) * 3 + 1];
        qz[i] = tmpl[(qbase + i) * 3 + 2];
        axq[i] = -qx[i]; ayq[i] = -qy[i]; azq[i] = -qz[i];
    }
    const float INFf = __uint_as_float(0x7f800000u);

    if (tid < 16) cnt[tid] = 0;

    // ---- phase A: per-lane chunk-min for each of 4 queries ----
    float cm[4];
    #pragma unroll
    for (int i = 0; i < 4; ++i) cm[i] = INFf;

    for (int slab = 0; slab < Nn / KSLAB; ++slab) {
        __syncthreads();
        #pragma unroll
        for (int k = 0; k < KSLAB / 256; ++k) {
            const int pl = tid + k * 256;
            const long e = (long)(slab * KSLAB + pl) * 3;
            const float x = tmpl[e], y = tmpl[e+1], z = tmpl[e+2];
            sp4[pl] = make_float4(x, y, z, 0.5f * (x*x + y*y + z*z));
        }
        __syncthreads();
        #pragma unroll 4
        for (int jj = 0; jj < KSLAB / 64; ++jj) {
            const float4 P = sp4[jj * 64 + c];          // contiguous: conflict-free
            #pragma unroll
            for (int i = 0; i < 4; ++i) {
                const float s = fmaf(P.x, axq[i], fmaf(P.y, ayq[i], fmaf(P.z, azq[i], P.w)));
                cm[i] = fminf(cm[i], s);
            }
        }
    }

    // ---- per-query threshold: 7th-smallest chunk-min via knockout butterfly ----
    float T[4];
    #pragma unroll
    for (int i = 0; i < 4; ++i) {
        float v = cm[i], h;
        #pragma unroll
        for (int t = 0; t < 7; ++t) {
            h = v;
            h = fminf(h, __shfl_xor(h, 32, 64));
            h = fminf(h, __shfl_xor(h, 16, 64));
            h = fminf(h, __shfl_xor(h, 8, 64));
            h = fminf(h, __shfl_xor(h, 4, 64));
            h = fminf(h, __shfl_xor(h, 2, 64));
            h = fminf(h, __shfl_xor(h, 1, 64));
            T[i] = h;
            if (v == h) v = INFf;   // knock out achieving chunk(s); bound stays valid
        }
    }

    // ---- phase B: collect candidates (s <= T) into LDS; rare ----
    for (int slab = 0; slab < Nn / KSLAB; ++slab) {
        __syncthreads();
        #pragma unroll
        for (int k = 0; k < KSLAB / 256; ++k) {
            const int pl = tid + k * 256;
            const long e = (long)(slab * KSLAB + pl) * 3;
            const float x = tmpl[e], y = tmpl[e+1], z = tmpl[e+2];
            sp4[pl] = make_float4(x, y, z, 0.5f * (x*x + y*y + z*z));
        }
        __syncthreads();
        #pragma unroll 2
        for (int jj = 0; jj < KSLAB / 64; ++jj) {
            const float4 P = sp4[jj * 64 + c];
            const int p = slab * KSLAB + jj * 64 + c;
            #pragma unroll
            for (int i = 0; i < 4; ++i) {
                const float s = fmaf(P.x, axq[i], fmaf(P.y, ayq[i], fmaf(P.z, azq[i], P.w)));
                if (s <= T[i]) {
                    const int slot = wid * 4 + i;
                    const int pos = atomicAdd(&cnt[slot], 1);
                    if (pos < KCAP)
                        cand[slot][pos] =
                            ((unsigned long long)ordkey(s) << 32) | (unsigned)p;
                }
            }
        }
    }
    __syncthreads();

    // ---- exact top-7 over candidates + smooth term; one thread per query ----
    if (tid < 16) {
        const int q = blockIdx.x * 16 + tid;
        const int m = min(cnt[tid], KCAP);
        unsigned long long l0 = ~0ULL, l1 = ~0ULL, l2 = ~0ULL, l3 = ~0ULL,
                           l4 = ~0ULL, l5 = ~0ULL, l6 = ~0ULL;
        for (int t = 0; t < m; ++t) {
            const unsigned long long key = cand[tid][t];
            if (key < l6) {
                l6 = key;
                if (l6 < l5) { auto tt = l5; l5 = l6; l6 = tt; }
                if (l5 < l4) { auto tt = l4; l4 = l5; l5 = tt; }
                if (l4 < l3) { auto tt = l3; l3 = l4; l4 = tt; }
                if (l3 < l2) { auto tt = l2; l2 = l3; l3 = tt; }
                if (l2 < l1) { auto tt = l1; l1 = l2; l2 = tt; }
                if (l1 < l0) { auto tt = l0; l0 = l1; l1 = tt; }
            }
        }
        // l0 = self (smallest key); neighbors l1..l6
        int nb[6] = { (int)(unsigned)l1, (int)(unsigned)l2, (int)(unsigned)l3,
                      (int)(unsigned)l4, (int)(unsigned)l5, (int)(unsigned)l6 };
        float s = 0.0f;
        #pragma unroll
        for (int k = 0; k < 6; ++k) {
            const int j = nb[k];
            #pragma unroll
            for (int b = 0; b < Bb; ++b) {
                const float* dn = disp + ((long)b * Nn + q) * 3;
                const float* dj = disp + ((long)b * Nn + j) * 3;
                const float ddx = dj[0] - dn[0];
                const float ddy = dj[1] - dn[1];
                const float ddz = dj[2] - dn[2];
                s += ddx*ddx + ddy*ddy + ddz*ddz;
            }
        }
        atomicAdd(&acc[3], s);
    }
}

// ---- fused tail: sqrt-of-mins sum + mat loss + disp reg ----
__global__ __launch_bounds__(256) void tail_reduce_kernel(
    const float* __restrict__ minArr, const float* __restrict__ pm,
    const float* __restrict__ tm, const float* __restrict__ dp,
    float* __restrict__ acc) {
    const int tid = threadIdx.x;
    const int stride = gridDim.x * blockDim.x;
    float sc = 0.0f, sm = 0.0f, sd = 0.0f;
    for (int i = blockIdx.x * blockDim.x + tid; i < 2 * Bb * Nn; i += stride) {
        sc += sqrtf(fmaxf(minArr[i], 1e-12f));
    }
    for (int i = blockIdx.x * blockDim.x + tid; i < Bb * Nn * 4; i += stride) {
        float d = pm[i] - tm[i];
        sm += d * d;
    }
    for (int i = blockIdx.x * blockDim.x + tid; i < Bb * Nn * 3; i += stride) {
        float v = dp[i];
        sd += v * v;
    }
    __shared__ float r0[256], r1[256], r2[256];
    r0[tid] = sc; r1[tid] = sm; r2[tid] = sd;
    __syncthreads();
    for (int w = 128; w > 0; w >>= 1) {
        if (tid < w) { r0[tid] += r0[tid + w]; r1[tid] += r1[tid + w]; r2[tid] += r2[tid + w]; }
        __syncthreads();
    }
    if (tid == 0) {
        atomicAdd(&acc[0], r0[0]);
        atomicAdd(&acc[1], r1[0]);
        atomicAdd(&acc[2], r2[0]);
    }
}

// ---------------- finalize ----------------
__global__ void finalize_kernel(const float* __restrict__ acc, float* __restrict__ out) {
    if (threadIdx.x == 0 && blockIdx.x == 0) {
        float cd  = acc[0] / (2.0f * Bb * Nn);
        float mat = acc[1] / (float)(Bb * Nn * 4);
        float dr  = acc[2] / (float)(Bb * Nn * 3);
        float sm  = acc[3] / (float)(Bb * Nn * KNB * 3);
        out[0] = 1.0f * cd + 0.1f * mat + 0.01f * dr + 0.005f * sm;
    }
}

}  // namespace

extern "C" void kernel_launch(void* const* d_in, const int* in_sizes, int n_in,
                              void* d_out, int out_size, void* d_ws, size_t ws_size,
                              hipStream_t stream) {
    const float* pred_disp  = (const float*)d_in[0];
    const float* pred_mat   = (const float*)d_in[1];
    const float* target_pos = (const float*)d_in[2];
    const float* target_mat = (const float*)d_in[3];
    const float* tmpl       = (const float*)d_in[4];

    float* ws = (float*)d_ws;
    unsigned* minArr = (unsigned*)ws;         // 2*B*N: [dir0: pred->targ][dir1: targ->pred]
    float* acc = ws + 2 * Bb * Nn;            // 8 accumulators

    init_ws_kernel<<<(2 * Bb * Nn) / 256, 256, 0, stream>>>(minArr, acc);

    dim3 cgrid(Nn / 256 / QPT, MCHUNKS, Bb * 2);   // (2, 32, 8) = 512 blocks
    chamfer_min_kernel<<<cgrid, 256, 0, stream>>>(pred_disp, tmpl, target_pos, minArr);

    knn_smooth_kernel<<<Nn / 16, 256, 0, stream>>>(tmpl, pred_disp, acc);  // 512 blocks

    tail_reduce_kernel<<<128, 256, 0, stream>>>((const float*)minArr, pred_mat, target_mat,
                                                pred_disp, acc);

    finalize_kernel<<<1, 64, 0, stream>>>(acc, (float*)d_out);
}

// Round 6
// 94.797 us; speedup vs baseline: 1.6710x; 1.1032x over previous
//
#include <hip/hip_runtime.h>

namespace {

constexpr int Bb = 4, Nn = 8192, Mm = 8192, KNB = 6;
constexpr int CH_TILE = 256, MCHUNKS = 32, QPT = 8;   // chamfer
constexpr int KCAP = 64;                              // knn candidate slots per query

__device__ inline unsigned ordkey(float f) {
    unsigned b = __float_as_uint(f);
    return b ^ (unsigned)(((int)b >> 31) | 0x80000000);
}

// ---------------- init: mins -> +inf, accumulators -> 0 ----------------
__global__ void init_ws_kernel(unsigned* __restrict__ minArr, float* __restrict__ acc) {
    int i = blockIdx.x * blockDim.x + threadIdx.x;
    if (i < 2 * Bb * Nn) minArr[i] = 0x7f800000u;  // +inf bits
    if (i < 8) acc[i] = 0.0f;
}

// ---------------- chamfer: both directions, 8 queries/thread ----------------
// dir 0: query = template+disp, db = target ; dir 1: query = target, db = template+disp
// s = h - q.p (h = |p|^2/2), d2 = 2*min(s) + |q|^2  == xx + yy - 2xy form
__global__ __launch_bounds__(256, 4) void chamfer_min_kernel(
    const float* __restrict__ disp, const float* __restrict__ tmpl,
    const float* __restrict__ targ, unsigned* __restrict__ outMin) {
    __shared__ float4 sp[CH_TILE];
    const int tid = threadIdx.x;
    const int dir = blockIdx.z & 1;
    const int b = blockIdx.z >> 1;
    const int mBase = blockIdx.y * CH_TILE;

    float ax[QPT], ay[QPT], az[QPT], mn[QPT];
    #pragma unroll
    for (int k = 0; k < QPT; ++k) {
        const int n = blockIdx.x * 256 + tid + k * (Nn / QPT);
        const long e = ((long)b * Nn + n) * 3;
        float x, y, z;
        if (dir == 0) {
            x = tmpl[e] + disp[e]; y = tmpl[e+1] + disp[e+1]; z = tmpl[e+2] + disp[e+2];
        } else {
            x = targ[e]; y = targ[e+1]; z = targ[e+2];
        }
        ax[k] = -x; ay[k] = -y; az[k] = -z;
        mn[k] = 1e38f;
    }
    {
        const long e = ((long)b * Mm + mBase + tid) * 3;
        float x, y, z;
        if (dir == 0) {
            x = targ[e]; y = targ[e+1]; z = targ[e+2];
        } else {
            x = tmpl[e] + disp[e]; y = tmpl[e+1] + disp[e+1]; z = tmpl[e+2] + disp[e+2];
        }
        sp[tid] = make_float4(x, y, z, 0.5f * (x*x + y*y + z*z));
    }
    __syncthreads();

    #pragma unroll 4
    for (int j = 0; j < CH_TILE; j += 2) {
        const float4 P0 = sp[j + 0];
        const float4 P1 = sp[j + 1];
        #pragma unroll
        for (int k = 0; k < QPT; ++k) {
            const float s0 = fmaf(P0.x, ax[k], fmaf(P0.y, ay[k], fmaf(P0.z, az[k], P0.w)));
            const float s1 = fmaf(P1.x, ax[k], fmaf(P1.y, ay[k], fmaf(P1.z, az[k], P1.w)));
            mn[k] = fminf(fminf(mn[k], s0), s1);   // fuses to v_min3_f32
        }
    }

    #pragma unroll
    for (int k = 0; k < QPT; ++k) {
        const int n = blockIdx.x * 256 + tid + k * (Nn / QPT);
        const float qs = ax[k]*ax[k] + ay[k]*ay[k] + az[k]*az[k];
        const float d2 = fmaf(2.0f, mn[k], qs);
        atomicMin(&outMin[((long)dir * Bb + b) * Nn + n], __float_as_uint(d2));
    }
}

// ---------------- KNN: template fully LDS-resident; 32 queries/block ----------------
// 512 threads = 8 waves; wave = 4 queries x 64 lane-chunks (stride-64 interleave).
__global__ __launch_bounds__(512, 1) void knn_smooth_kernel(
    const float* __restrict__ tmpl, const float* __restrict__ disp,
    float* __restrict__ acc) {
    __shared__ float4 sp4[Nn];                     // 128 KB, point-major
    __shared__ unsigned long long cand[32][KCAP];  // 16 KB
    __shared__ int cnt[32];
    __shared__ float part[32];

    const int tid = threadIdx.x;
    const int lane = tid & 63;
    const int wid = tid >> 6;           // wave 0..7
    const int c = lane;                 // chunk class

    const int qbase = blockIdx.x * 32 + wid * 4;
    float axq[4], ayq[4], azq[4];
    #pragma unroll
    for (int i = 0; i < 4; ++i) {
        axq[i] = -tmpl[(qbase + i) * 3 + 0];
        ayq[i] = -tmpl[(qbase + i) * 3 + 1];
        azq[i] = -tmpl[(qbase + i) * 3 + 2];
    }
    const float INFf = __uint_as_float(0x7f800000u);

    if (tid < 32) cnt[tid] = 0;

    // ---- stage entire template once ----
    #pragma unroll
    for (int k = 0; k < Nn / 512; ++k) {
        const int pl = tid + k * 512;
        const long e = (long)pl * 3;
        const float x = tmpl[e], y = tmpl[e+1], z = tmpl[e+2];
        sp4[pl] = make_float4(x, y, z, 0.5f * (x*x + y*y + z*z));
    }
    __syncthreads();

    // ---- phase A: per-lane chunk-min for each of 4 queries ----
    float cm[4];
    #pragma unroll
    for (int i = 0; i < 4; ++i) cm[i] = INFf;

    #pragma unroll 2
    for (int jj = 0; jj < Nn / 64; jj += 2) {
        const float4 P0 = sp4[(jj + 0) * 64 + c];
        const float4 P1 = sp4[(jj + 1) * 64 + c];
        #pragma unroll
        for (int i = 0; i < 4; ++i) {
            const float s0 = fmaf(P0.x, axq[i], fmaf(P0.y, ayq[i], fmaf(P0.z, azq[i], P0.w)));
            const float s1 = fmaf(P1.x, axq[i], fmaf(P1.y, ayq[i], fmaf(P1.z, azq[i], P1.w)));
            cm[i] = fminf(fminf(cm[i], s0), s1);
        }
    }

    // ---- per-query threshold T = 7th-smallest chunk-min (knockout butterfly) ----
    float T[4];
    #pragma unroll
    for (int i = 0; i < 4; ++i) {
        float v = cm[i], h;
        #pragma unroll
        for (int t = 0; t < 7; ++t) {
            h = v;
            h = fminf(h, __shfl_xor(h, 32, 64));
            h = fminf(h, __shfl_xor(h, 16, 64));
            h = fminf(h, __shfl_xor(h, 8, 64));
            h = fminf(h, __shfl_xor(h, 4, 64));
            h = fminf(h, __shfl_xor(h, 2, 64));
            h = fminf(h, __shfl_xor(h, 1, 64));
            T[i] = h;
            if (v == h) v = INFf;   // knock out achieving chunk(s); >=7 pts <= T guaranteed
        }
    }

    // ---- phase B: collect candidates (s <= T) from LDS; rare ----
    #pragma unroll 2
    for (int jj = 0; jj < Nn / 64; ++jj) {
        const float4 P = sp4[jj * 64 + c];
        const int p = jj * 64 + c;
        #pragma unroll
        for (int i = 0; i < 4; ++i) {
            const float s = fmaf(P.x, axq[i], fmaf(P.y, ayq[i], fmaf(P.z, azq[i], P.w)));
            if (s <= T[i]) {
                const int slot = wid * 4 + i;
                const int pos = atomicAdd(&cnt[slot], 1);
                if (pos < KCAP)
                    cand[slot][pos] =
                        ((unsigned long long)ordkey(s) << 32) | (unsigned)p;
            }
        }
    }
    __syncthreads();

    // ---- exact top-7 over candidates + smooth term; one thread per query ----
    float s = 0.0f;
    if (tid < 32) {
        const int q = blockIdx.x * 32 + tid;
        const int m = min(cnt[tid], KCAP);
        unsigned long long l0 = ~0ULL, l1 = ~0ULL, l2 = ~0ULL, l3 = ~0ULL,
                           l4 = ~0ULL, l5 = ~0ULL, l6 = ~0ULL;
        for (int t = 0; t < m; ++t) {
            const unsigned long long key = cand[tid][t];
            if (key < l6) {
                l6 = key;
                if (l6 < l5) { auto tt = l5; l5 = l6; l6 = tt; }
                if (l5 < l4) { auto tt = l4; l4 = l5; l5 = tt; }
                if (l4 < l3) { auto tt = l3; l3 = l4; l4 = tt; }
                if (l3 < l2) { auto tt = l2; l2 = l3; l3 = tt; }
                if (l2 < l1) { auto tt = l1; l1 = l2; l2 = tt; }
                if (l1 < l0) { auto tt = l0; l0 = l1; l1 = tt; }
            }
        }
        // l0 = self (smallest key); neighbors l1..l6
        int nb[6] = { (int)(unsigned)l1, (int)(unsigned)l2, (int)(unsigned)l3,
                      (int)(unsigned)l4, (int)(unsigned)l5, (int)(unsigned)l6 };
        #pragma unroll
        for (int k = 0; k < 6; ++k) {
            const int j = nb[k];
            #pragma unroll
            for (int b = 0; b < Bb; ++b) {
                const float* dn = disp + ((long)b * Nn + q) * 3;
                const float* dj = disp + ((long)b * Nn + j) * 3;
                const float ddx = dj[0] - dn[0];
                const float ddy = dj[1] - dn[1];
                const float ddz = dj[2] - dn[2];
                s += ddx*ddx + ddy*ddy + ddz*ddz;
            }
        }
        part[tid] = s;
    }
    __syncthreads();
    if (tid == 0) {
        float tot = 0.0f;
        #pragma unroll
        for (int i = 0; i < 32; ++i) tot += part[i];
        atomicAdd(&acc[3], tot);   // one atomic per block
    }
}

// ---- fused tail: sqrt-of-mins sum + mat loss + disp reg ----
__global__ __launch_bounds__(256) void tail_reduce_kernel(
    const float* __restrict__ minArr, const float* __restrict__ pm,
    const float* __restrict__ tm, const float* __restrict__ dp,
    float* __restrict__ acc) {
    const int tid = threadIdx.x;
    const int stride = gridDim.x * blockDim.x;
    float sc = 0.0f, sm = 0.0f, sd = 0.0f;
    for (int i = blockIdx.x * blockDim.x + tid; i < 2 * Bb * Nn; i += stride) {
        sc += sqrtf(fmaxf(minArr[i], 1e-12f));
    }
    for (int i = blockIdx.x * blockDim.x + tid; i < Bb * Nn * 4; i += stride) {
        float d = pm[i] - tm[i];
        sm += d * d;
    }
    for (int i = blockIdx.x * blockDim.x + tid; i < Bb * Nn * 3; i += stride) {
        float v = dp[i];
        sd += v * v;
    }
    __shared__ float r0[256], r1[256], r2[256];
    r0[tid] = sc; r1[tid] = sm; r2[tid] = sd;
    __syncthreads();
    for (int w = 128; w > 0; w >>= 1) {
        if (tid < w) { r0[tid] += r0[tid + w]; r1[tid] += r1[tid + w]; r2[tid] += r2[tid + w]; }
        __syncthreads();
    }
    if (tid == 0) {
        atomicAdd(&acc[0], r0[0]);
        atomicAdd(&acc[1], r1[0]);
        atomicAdd(&acc[2], r2[0]);
    }
}

// ---------------- finalize ----------------
__global__ void finalize_kernel(const float* __restrict__ acc, float* __restrict__ out) {
    if (threadIdx.x == 0 && blockIdx.x == 0) {
        float cd  = acc[0] / (2.0f * Bb * Nn);
        float mat = acc[1] / (float)(Bb * Nn * 4);
        float dr  = acc[2] / (float)(Bb * Nn * 3);
        float sm  = acc[3] / (float)(Bb * Nn * KNB * 3);
        out[0] = 1.0f * cd + 0.1f * mat + 0.01f * dr + 0.005f * sm;
    }
}

}  // namespace

extern "C" void kernel_launch(void* const* d_in, const int* in_sizes, int n_in,
                              void* d_out, int out_size, void* d_ws, size_t ws_size,
                              hipStream_t stream) {
    const float* pred_disp  = (const float*)d_in[0];
    const float* pred_mat   = (const float*)d_in[1];
    const float* target_pos = (const float*)d_in[2];
    const float* target_mat = (const float*)d_in[3];
    const float* tmpl       = (const float*)d_in[4];

    float* ws = (float*)d_ws;
    unsigned* minArr = (unsigned*)ws;         // 2*B*N: [dir0: pred->targ][dir1: targ->pred]
    float* acc = ws + 2 * Bb * Nn;            // 8 accumulators

    init_ws_kernel<<<(2 * Bb * Nn) / 256, 256, 0, stream>>>(minArr, acc);

    dim3 cgrid(Nn / 256 / QPT, MCHUNKS, Bb * 2);   // (4, 32, 8) = 1024 blocks
    chamfer_min_kernel<<<cgrid, 256, 0, stream>>>(pred_disp, tmpl, target_pos, minArr);

    knn_smooth_kernel<<<Nn / 32, 512, 0, stream>>>(tmpl, pred_disp, acc);  // 256 blocks

    tail_reduce_kernel<<<128, 256, 0, stream>>>((const float*)minArr, pred_mat, target_mat,
                                                pred_disp, acc);

    finalize_kernel<<<1, 64, 0, stream>>>(acc, (float*)d_out);
}

// Round 7
// 93.691 us; speedup vs baseline: 1.6907x; 1.0118x over previous
//
#include <hip/hip_runtime.h>

namespace {

constexpr int Bb = 4, Nn = 8192, Mm = 8192, KNB = 6;
constexpr int CH_TILE = 256, MCHUNKS = 32, QPT = 8;   // chamfer
constexpr int CH_BLOCKS = (Nn / 256 / QPT) * MCHUNKS * Bb * 2;  // 4*32*8 = 1024
constexpr int KSLAB = 1024;                           // knn slab points (16 KB)
constexpr int KCAP = 64;                              // candidate slots per query
constexpr int KNN_BLOCKS = Nn / 16;                   // 512
constexpr int TAIL_BLOCKS = 128;

__device__ inline unsigned ordkey(float f) {
    unsigned b = __float_as_uint(f);
    return b ^ (unsigned)(((int)b >> 31) | 0x80000000);
}

union SMemU {
    float4 ch_sp[CH_TILE];                       // chamfer: 4 KB
    struct {
        float4 sp4[KSLAB];                       // 16 KB
        unsigned long long cand[16][KCAP];       // 8 KB
        int cnt[16];
        float part[16];
    } knn;                                       // 24.7 KB
};

// ---------------- init: mins -> huge, accumulators -> 0 ----------------
__global__ void init_ws_kernel(unsigned* __restrict__ minArr, float* __restrict__ acc) {
    int i = blockIdx.x * blockDim.x + threadIdx.x;
    if (i < 2 * Bb * Nn) minArr[i] = 0x7f800000u;  // +inf bits
    if (i < 8) acc[i] = 0.0f;                      // acc[7] doubles as uint counter
}

// ---------------- fat kernel: chamfer blocks + knn blocks ----------------
__global__ __launch_bounds__(256, 4) void fat_kernel(
    const float* __restrict__ disp, const float* __restrict__ tmpl,
    const float* __restrict__ targ, unsigned* __restrict__ outMin,
    float* __restrict__ acc) {
    __shared__ SMemU sm;
    const int tid = threadIdx.x;

    if (blockIdx.x < CH_BLOCKS) {
        // ================= chamfer =================
        const int cb = blockIdx.x;
        const int bx = cb & 3;
        const int by = (cb >> 2) & 31;
        const int dir = (cb >> 7) & 1;
        const int b = cb >> 8;
        const int mBase = by * CH_TILE;

        float ax[QPT], ay[QPT], az[QPT], mn[QPT];
        #pragma unroll
        for (int k = 0; k < QPT; ++k) {
            const int n = bx * 256 + tid + k * (Nn / QPT);
            const long e = ((long)b * Nn + n) * 3;
            float x, y, z;
            if (dir == 0) {
                x = tmpl[e] + disp[e]; y = tmpl[e+1] + disp[e+1]; z = tmpl[e+2] + disp[e+2];
            } else {
                x = targ[e]; y = targ[e+1]; z = targ[e+2];
            }
            ax[k] = -x; ay[k] = -y; az[k] = -z;
            mn[k] = 1e38f;
        }
        {
            const long e = ((long)b * Mm + mBase + tid) * 3;
            float x, y, z;
            if (dir == 0) {
                x = targ[e]; y = targ[e+1]; z = targ[e+2];
            } else {
                x = tmpl[e] + disp[e]; y = tmpl[e+1] + disp[e+1]; z = tmpl[e+2] + disp[e+2];
            }
            sm.ch_sp[tid] = make_float4(x, y, z, 0.5f * (x*x + y*y + z*z));
        }
        __syncthreads();

        #pragma unroll 4
        for (int j = 0; j < CH_TILE; j += 2) {
            const float4 P0 = sm.ch_sp[j + 0];
            const float4 P1 = sm.ch_sp[j + 1];
            #pragma unroll
            for (int k = 0; k < QPT; ++k) {
                const float s0 = fmaf(P0.x, ax[k], fmaf(P0.y, ay[k], fmaf(P0.z, az[k], P0.w)));
                const float s1 = fmaf(P1.x, ax[k], fmaf(P1.y, ay[k], fmaf(P1.z, az[k], P1.w)));
                mn[k] = fminf(fminf(mn[k], s0), s1);   // v_min3_f32
            }
        }

        #pragma unroll
        for (int k = 0; k < QPT; ++k) {
            const int n = bx * 256 + tid + k * (Nn / QPT);
            const float qs = ax[k]*ax[k] + ay[k]*ay[k] + az[k]*az[k];
            const float d2 = fmaf(2.0f, mn[k], qs);
            atomicMin(&outMin[((long)dir * Bb + b) * Nn + n], __float_as_uint(d2));
        }
    } else {
        // ================= knn + smooth =================
        const int kb = blockIdx.x - CH_BLOCKS;
        const int lane = tid & 63;
        const int wid = tid >> 6;           // wave 0..3
        const int c = lane;                 // chunk class (p mod 64)

        const int qbase = kb * 16 + wid * 4;
        float axq[4], ayq[4], azq[4];
        #pragma unroll
        for (int i = 0; i < 4; ++i) {
            axq[i] = -tmpl[(qbase + i) * 3 + 0];
            ayq[i] = -tmpl[(qbase + i) * 3 + 1];
            azq[i] = -tmpl[(qbase + i) * 3 + 2];
        }
        const float INFf = __uint_as_float(0x7f800000u);

        if (tid < 16) sm.knn.cnt[tid] = 0;

        // ---- phase A: per-lane chunk-min for each of 4 queries ----
        float cm[4];
        #pragma unroll
        for (int i = 0; i < 4; ++i) cm[i] = INFf;

        for (int slab = 0; slab < Nn / KSLAB; ++slab) {
            __syncthreads();
            #pragma unroll
            for (int k = 0; k < KSLAB / 256; ++k) {
                const int pl = tid + k * 256;
                const long e = (long)(slab * KSLAB + pl) * 3;
                const float x = tmpl[e], y = tmpl[e+1], z = tmpl[e+2];
                sm.knn.sp4[pl] = make_float4(x, y, z, 0.5f * (x*x + y*y + z*z));
            }
            __syncthreads();
            #pragma unroll 2
            for (int jj = 0; jj < KSLAB / 64; jj += 2) {
                const float4 P0 = sm.knn.sp4[(jj + 0) * 64 + c];
                const float4 P1 = sm.knn.sp4[(jj + 1) * 64 + c];
                #pragma unroll
                for (int i = 0; i < 4; ++i) {
                    const float s0 = fmaf(P0.x, axq[i], fmaf(P0.y, ayq[i], fmaf(P0.z, azq[i], P0.w)));
                    const float s1 = fmaf(P1.x, axq[i], fmaf(P1.y, ayq[i], fmaf(P1.z, azq[i], P1.w)));
                    cm[i] = fminf(fminf(cm[i], s0), s1);
                }
            }
        }

        // ---- per-query threshold T = 7th-smallest chunk-min (knockout) ----
        float T[4];
        #pragma unroll
        for (int i = 0; i < 4; ++i) {
            float v = cm[i], h;
            #pragma unroll
            for (int t = 0; t < 7; ++t) {
                h = v;
                h = fminf(h, __shfl_xor(h, 32, 64));
                h = fminf(h, __shfl_xor(h, 16, 64));
                h = fminf(h, __shfl_xor(h, 8, 64));
                h = fminf(h, __shfl_xor(h, 4, 64));
                h = fminf(h, __shfl_xor(h, 2, 64));
                h = fminf(h, __shfl_xor(h, 1, 64));
                T[i] = h;
                if (v == h) v = INFf;   // >=7 chunks knocked out => >=7 pts <= T
            }
        }

        // ---- phase B: collect candidates (s <= T); rare ----
        for (int slab = 0; slab < Nn / KSLAB; ++slab) {
            __syncthreads();
            #pragma unroll
            for (int k = 0; k < KSLAB / 256; ++k) {
                const int pl = tid + k * 256;
                const long e = (long)(slab * KSLAB + pl) * 3;
                const float x = tmpl[e], y = tmpl[e+1], z = tmpl[e+2];
                sm.knn.sp4[pl] = make_float4(x, y, z, 0.5f * (x*x + y*y + z*z));
            }
            __syncthreads();
            #pragma unroll 2
            for (int jj = 0; jj < KSLAB / 64; ++jj) {
                const float4 P = sm.knn.sp4[jj * 64 + c];
                const int p = slab * KSLAB + jj * 64 + c;
                #pragma unroll
                for (int i = 0; i < 4; ++i) {
                    const float s = fmaf(P.x, axq[i], fmaf(P.y, ayq[i], fmaf(P.z, azq[i], P.w)));
                    if (s <= T[i]) {
                        const int slot = wid * 4 + i;
                        const int pos = atomicAdd(&sm.knn.cnt[slot], 1);
                        if (pos < KCAP)
                            sm.knn.cand[slot][pos] =
                                ((unsigned long long)ordkey(s) << 32) | (unsigned)p;
                    }
                }
            }
        }
        __syncthreads();

        // ---- exact top-7 over candidates + smooth term; one thread/query ----
        if (tid < 16) {
            const int q = kb * 16 + tid;
            const int m = min(sm.knn.cnt[tid], KCAP);
            unsigned long long l0 = ~0ULL, l1 = ~0ULL, l2 = ~0ULL, l3 = ~0ULL,
                               l4 = ~0ULL, l5 = ~0ULL, l6 = ~0ULL;
            for (int t = 0; t < m; ++t) {
                const unsigned long long key = sm.knn.cand[tid][t];
                if (key < l6) {
                    l6 = key;
                    if (l6 < l5) { auto tt = l5; l5 = l6; l6 = tt; }
                    if (l5 < l4) { auto tt = l4; l4 = l5; l5 = tt; }
                    if (l4 < l3) { auto tt = l3; l3 = l4; l4 = tt; }
                    if (l3 < l2) { auto tt = l2; l2 = l3; l3 = tt; }
                    if (l2 < l1) { auto tt = l1; l1 = l2; l2 = tt; }
                    if (l1 < l0) { auto tt = l0; l0 = l1; l1 = tt; }
                }
            }
            // l0 = self; neighbors l1..l6
            int nb[6] = { (int)(unsigned)l1, (int)(unsigned)l2, (int)(unsigned)l3,
                          (int)(unsigned)l4, (int)(unsigned)l5, (int)(unsigned)l6 };
            float s = 0.0f;
            #pragma unroll
            for (int k = 0; k < 6; ++k) {
                const int j = nb[k];
                #pragma unroll
                for (int b = 0; b < Bb; ++b) {
                    const float* dn = disp + ((long)b * Nn + q) * 3;
                    const float* dj = disp + ((long)b * Nn + j) * 3;
                    const float ddx = dj[0] - dn[0];
                    const float ddy = dj[1] - dn[1];
                    const float ddz = dj[2] - dn[2];
                    s += ddx*ddx + ddy*ddy + ddz*ddz;
                }
            }
            sm.knn.part[tid] = s;
        }
        __syncthreads();
        if (tid == 0) {
            float tot = 0.0f;
            #pragma unroll
            for (int i = 0; i < 16; ++i) tot += sm.knn.part[i];
            atomicAdd(&acc[3], tot);   // one atomic per knn block
        }
    }
}

// ---- fused tail: reductions + last-block finalize ----
__global__ __launch_bounds__(256) void tail_reduce_kernel(
    const float* __restrict__ minArr, const float* __restrict__ pm,
    const float* __restrict__ tm, const float* __restrict__ dp,
    float* __restrict__ acc, float* __restrict__ out) {
    const int tid = threadIdx.x;
    const int stride = gridDim.x * blockDim.x;
    float sc = 0.0f, sm = 0.0f, sd = 0.0f;
    for (int i = blockIdx.x * blockDim.x + tid; i < 2 * Bb * Nn; i += stride) {
        sc += sqrtf(fmaxf(minArr[i], 1e-12f));
    }
    for (int i = blockIdx.x * blockDim.x + tid; i < Bb * Nn * 4; i += stride) {
        float d = pm[i] - tm[i];
        sm += d * d;
    }
    for (int i = blockIdx.x * blockDim.x + tid; i < Bb * Nn * 3; i += stride) {
        float v = dp[i];
        sd += v * v;
    }
    __shared__ float r0[256], r1[256], r2[256];
    r0[tid] = sc; r1[tid] = sm; r2[tid] = sd;
    __syncthreads();
    for (int w = 128; w > 0; w >>= 1) {
        if (tid < w) { r0[tid] += r0[tid + w]; r1[tid] += r1[tid + w]; r2[tid] += r2[tid + w]; }
        __syncthreads();
    }
    if (tid == 0) {
        atomicAdd(&acc[0], r0[0]);
        atomicAdd(&acc[1], r1[0]);
        atomicAdd(&acc[2], r2[0]);
        __threadfence();
        const unsigned done = atomicAdd((unsigned*)&acc[7], 1u);
        if (done == (unsigned)(gridDim.x - 1)) {
            // last block: coherent reads via atomic RMW (+0)
            const float c0 = atomicAdd(&acc[0], 0.0f);
            const float c1 = atomicAdd(&acc[1], 0.0f);
            const float c2 = atomicAdd(&acc[2], 0.0f);
            const float c3 = atomicAdd(&acc[3], 0.0f);
            const float cd  = c0 / (2.0f * Bb * Nn);
            const float mat = c1 / (float)(Bb * Nn * 4);
            const float dr  = c2 / (float)(Bb * Nn * 3);
            const float smo = c3 / (float)(Bb * Nn * KNB * 3);
            out[0] = 1.0f * cd + 0.1f * mat + 0.01f * dr + 0.005f * smo;
        }
    }
}

}  // namespace

extern "C" void kernel_launch(void* const* d_in, const int* in_sizes, int n_in,
                              void* d_out, int out_size, void* d_ws, size_t ws_size,
                              hipStream_t stream) {
    const float* pred_disp  = (const float*)d_in[0];
    const float* pred_mat   = (const float*)d_in[1];
    const float* target_pos = (const float*)d_in[2];
    const float* target_mat = (const float*)d_in[3];
    const float* tmpl       = (const float*)d_in[4];

    float* ws = (float*)d_ws;
    unsigned* minArr = (unsigned*)ws;         // 2*B*N: [dir0: pred->targ][dir1: targ->pred]
    float* acc = ws + 2 * Bb * Nn;            // 8 accumulators (acc[7] = block counter)

    init_ws_kernel<<<(2 * Bb * Nn) / 256, 256, 0, stream>>>(minArr, acc);

    fat_kernel<<<CH_BLOCKS + KNN_BLOCKS, 256, 0, stream>>>(
        pred_disp, tmpl, target_pos, minArr, acc);

    tail_reduce_kernel<<<TAIL_BLOCKS, 256, 0, stream>>>(
        (const float*)minArr, pred_mat, target_mat, pred_disp, acc, (float*)d_out);
}

// Round 10
// 89.429 us; speedup vs baseline: 1.7713x; 1.0477x over previous
//
#include <hip/hip_runtime.h>

namespace {

typedef _Float16 half8 __attribute__((ext_vector_type(8)));
typedef float f32x16 __attribute__((ext_vector_type(16)));

constexpr int Bb = 4, Nn = 8192, Mm = 8192, KNB = 6;
constexpr int KSLAB = 1024;                  // knn slab points (16 KB)
constexpr int KCAP = 64;                     // knn candidate slots per query
constexpr int KNN_BLOCKS = Nn / 16;          // 512
constexpr int CHB = 256;                     // chamfer-mfma blocks (8 bd * 32)
constexpr int CH_CHUNK = 1024;               // points per staged chunk = 32 tiles
constexpr int TAIL_BLOCKS = 128;

union SMemU {
    half8 aF[32 * 64];                       // chamfer A-frags: 32 KB
    struct {
        float4 sp4[KSLAB];                   // 16 KB
        unsigned long long cand[16][KCAP];   // 8 KB
        int cnt[16];
        float part[16];
    } knn;                                   // ~24.7 KB
};

__device__ inline unsigned ordkey(float f) {
    unsigned b = __float_as_uint(f);
    return b ^ (unsigned)(((int)b >> 31) | 0x80000000);
}

__device__ inline half8 zero8() {
    half8 v;
    #pragma unroll
    for (int i = 0; i < 8; ++i) v[i] = (_Float16)0;
    return v;
}

// position loader: sel 0 = pred (tmpl+disp), sel 1 = targ
__device__ inline void load_pos(int sel, const float* __restrict__ disp,
                                const float* __restrict__ tmpl,
                                const float* __restrict__ targ,
                                int b, int i, float& x, float& y, float& z) {
    const long e = ((long)b * Nn + i) * 3;
    if (sel == 0) {
        x = tmpl[e] + disp[e]; y = tmpl[e + 1] + disp[e + 1]; z = tmpl[e + 2] + disp[e + 2];
    } else {
        x = targ[e]; y = targ[e + 1]; z = targ[e + 2];
    }
}

// Consistent single-f16 scheme (kg0 slots only; kg1 all zero on both sides):
//   acc = -p̂·q̂ + |p̂|²/2  (p̂,q̂ = f16-rounded coords; products exact in f32)
//   d2  = |q̂|² + 2·acc = |q̂-p̂|² ± 7e-6   (≥ ~0 by construction)
__device__ inline half8 a_frag(float x, float y, float z) {
    _Float16 hx = (_Float16)x, hy = (_Float16)y, hz = (_Float16)z;
    const float xr = (float)hx, yr = (float)hy, zr = (float)hz;
    const float pp5 = 0.5f * (xr * xr + yr * yr + zr * zr);
    _Float16 ph = (_Float16)pp5, pl = (_Float16)(pp5 - (float)ph);
    half8 v;
    v[0] = -hx; v[1] = -hy; v[2] = -hz; v[3] = ph; v[4] = pl;
    v[5] = (_Float16)0; v[6] = (_Float16)0; v[7] = (_Float16)0;
    return v;
}
__device__ inline half8 b_frag(float x, float y, float z) {
    _Float16 hx = (_Float16)x, hy = (_Float16)y, hz = (_Float16)z;
    half8 v;
    v[0] = hx; v[1] = hy; v[2] = hz; v[3] = (_Float16)1; v[4] = (_Float16)1;
    v[5] = (_Float16)0; v[6] = (_Float16)0; v[7] = (_Float16)0;
    return v;
}

// ---------------- init: accumulators -> 0 ----------------
__global__ void init_ws_kernel(float* __restrict__ acc) {
    if (threadIdx.x < 8) acc[threadIdx.x] = 0.0f;   // acc[7] doubles as uint counter
}

// ---------------- fat kernel: knn blocks [0,512) + chamfer-mfma blocks [512,768) ----
__global__ __launch_bounds__(256, 3) void fat_kernel(
    const float* __restrict__ disp, const float* __restrict__ tmpl,
    const float* __restrict__ targ, float* __restrict__ outMin,
    float* __restrict__ acc) {
    __shared__ SMemU sm;
    const int tid = threadIdx.x;

    if (blockIdx.x >= KNN_BLOCKS) {
        // ================= chamfer via MFMA =================
        const int cb = (int)blockIdx.x - KNN_BLOCKS;   // 0..255
        const int bd = cb >> 5;                        // 0..7
        const int qb = (cb & 31) * 256;
        const int dir = bd & 1, b = bd >> 1;
        const int qsel = dir;          // dir0: queries = pred; dir1: queries = targ
        const int psel = dir ^ 1;      // points are the other set
        const int lane = tid & 63, w = tid >> 6;
        const int l31 = lane & 31, kg = lane >> 5;

        float qq[2];
        half8 Bf[2];
        #pragma unroll
        for (int j = 0; j < 2; ++j) {
            const int q = qb + w * 64 + j * 32 + l31;
            float x, y, z;
            load_pos(qsel, disp, tmpl, targ, b, q, x, y, z);
            // round coords to f16 and compute qq from the ROUNDED values
            _Float16 hx = (_Float16)x, hy = (_Float16)y, hz = (_Float16)z;
            const float xr = (float)hx, yr = (float)hy, zr = (float)hz;
            qq[j] = xr * xr + yr * yr + zr * zr;
            Bf[j] = (kg == 0) ? b_frag(x, y, z) : zero8();
        }

        float run0 = 1e38f, run1 = 1e38f;
        const f32x16 zc = {0.f, 0.f, 0.f, 0.f, 0.f, 0.f, 0.f, 0.f,
                           0.f, 0.f, 0.f, 0.f, 0.f, 0.f, 0.f, 0.f};

        for (int ch = 0; ch < Nn / CH_CHUNK; ++ch) {
            __syncthreads();
            #pragma unroll
            for (int k = 0; k < (32 * 64) / 256; ++k) {
                const int e = tid + k * 256;
                const int er = e & 31, ekg = (e >> 5) & 1, tt = e >> 6;
                const int p = ch * CH_CHUNK + tt * 32 + er;
                float x, y, z;
                load_pos(psel, disp, tmpl, targ, b, p, x, y, z);
                sm.aF[e] = (ekg == 0) ? a_frag(x, y, z) : zero8();
            }
            __syncthreads();
            #pragma unroll 8
            for (int tt = 0; tt < 32; ++tt) {
                const half8 a = sm.aF[tt * 64 + lane];
                f32x16 c0 = __builtin_amdgcn_mfma_f32_32x32x16_f16(a, Bf[0], zc, 0, 0, 0);
                f32x16 c1 = __builtin_amdgcn_mfma_f32_32x32x16_f16(a, Bf[1], zc, 0, 0, 0);
                #pragma unroll
                for (int r = 0; r < 16; r += 2) {
                    run0 = fminf(run0, fminf(c0[r], c0[r + 1]));  // -> v_min3_f32
                    run1 = fminf(run1, fminf(c1[r], c1[r + 1]));
                }
            }
        }

        run0 = fminf(run0, __shfl_xor(run0, 32, 64));
        run1 = fminf(run1, __shfl_xor(run1, 32, 64));
        if (lane < 32) {
            const long base = ((long)dir * Bb + b) * Nn;
            {
                const int q = qb + w * 64 + l31;
                outMin[base + q] = fmaxf(fmaf(2.0f, run0, qq[0]), 0.0f);
            }
            {
                const int q = qb + w * 64 + 32 + l31;
                outMin[base + q] = fmaxf(fmaf(2.0f, run1, qq[1]), 0.0f);
            }
        }
    } else {
        // ================= knn + smooth (unchanged, verified) =================
        const int kb = blockIdx.x;
        const int lane = tid & 63;
        const int wid = tid >> 6;
        const int c = lane;

        const int qbase = kb * 16 + wid * 4;
        float axq[4], ayq[4], azq[4];
        #pragma unroll
        for (int i = 0; i < 4; ++i) {
            axq[i] = -tmpl[(qbase + i) * 3 + 0];
            ayq[i] = -tmpl[(qbase + i) * 3 + 1];
            azq[i] = -tmpl[(qbase + i) * 3 + 2];
        }
        const float INFf = __uint_as_float(0x7f800000u);

        if (tid < 16) sm.knn.cnt[tid] = 0;

        float cm[4];
        #pragma unroll
        for (int i = 0; i < 4; ++i) cm[i] = INFf;

        for (int slab = 0; slab < Nn / KSLAB; ++slab) {
            __syncthreads();
            #pragma unroll
            for (int k = 0; k < KSLAB / 256; ++k) {
                const int pl = tid + k * 256;
                const long e = (long)(slab * KSLAB + pl) * 3;
                const float x = tmpl[e], y = tmpl[e + 1], z = tmpl[e + 2];
                sm.knn.sp4[pl] = make_float4(x, y, z, 0.5f * (x * x + y * y + z * z));
            }
            __syncthreads();
            #pragma unroll 2
            for (int jj = 0; jj < KSLAB / 64; jj += 2) {
                const float4 P0 = sm.knn.sp4[(jj + 0) * 64 + c];
                const float4 P1 = sm.knn.sp4[(jj + 1) * 64 + c];
                #pragma unroll
                for (int i = 0; i < 4; ++i) {
                    const float s0 = fmaf(P0.x, axq[i], fmaf(P0.y, ayq[i], fmaf(P0.z, azq[i], P0.w)));
                    const float s1 = fmaf(P1.x, axq[i], fmaf(P1.y, ayq[i], fmaf(P1.z, azq[i], P1.w)));
                    cm[i] = fminf(fminf(cm[i], s0), s1);
                }
            }
        }

        float T[4];
        #pragma unroll
        for (int i = 0; i < 4; ++i) {
            float v = cm[i], h;
            #pragma unroll
            for (int t = 0; t < 7; ++t) {
                h = v;
                h = fminf(h, __shfl_xor(h, 32, 64));
                h = fminf(h, __shfl_xor(h, 16, 64));
                h = fminf(h, __shfl_xor(h, 8, 64));
                h = fminf(h, __shfl_xor(h, 4, 64));
                h = fminf(h, __shfl_xor(h, 2, 64));
                h = fminf(h, __shfl_xor(h, 1, 64));
                T[i] = h;
                if (v == h) v = INFf;   // >=7 chunks knocked out => >=7 pts <= T
            }
        }

        for (int slab = 0; slab < Nn / KSLAB; ++slab) {
            __syncthreads();
            #pragma unroll
            for (int k = 0; k < KSLAB / 256; ++k) {
                const int pl = tid + k * 256;
                const long e = (long)(slab * KSLAB + pl) * 3;
                const float x = tmpl[e], y = tmpl[e + 1], z = tmpl[e + 2];
                sm.knn.sp4[pl] = make_float4(x, y, z, 0.5f * (x * x + y * y + z * z));
            }
            __syncthreads();
            #pragma unroll 2
            for (int jj = 0; jj < KSLAB / 64; ++jj) {
                const float4 P = sm.knn.sp4[jj * 64 + c];
                const int p = slab * KSLAB + jj * 64 + c;
                #pragma unroll
                for (int i = 0; i < 4; ++i) {
                    const float s = fmaf(P.x, axq[i], fmaf(P.y, ayq[i], fmaf(P.z, azq[i], P.w)));
                    if (s <= T[i]) {
                        const int slot = wid * 4 + i;
                        const int pos = atomicAdd(&sm.knn.cnt[slot], 1);
                        if (pos < KCAP)
                            sm.knn.cand[slot][pos] =
                                ((unsigned long long)ordkey(s) << 32) | (unsigned)p;
                    }
                }
            }
        }
        __syncthreads();

        if (tid < 16) {
            const int q = kb * 16 + tid;
            const int m = min(sm.knn.cnt[tid], KCAP);
            unsigned long long l0 = ~0ULL, l1 = ~0ULL, l2 = ~0ULL, l3 = ~0ULL,
                               l4 = ~0ULL, l5 = ~0ULL, l6 = ~0ULL;
            for (int t = 0; t < m; ++t) {
                const unsigned long long key = sm.knn.cand[tid][t];
                if (key < l6) {
                    l6 = key;
                    if (l6 < l5) { auto tt = l5; l5 = l6; l6 = tt; }
                    if (l5 < l4) { auto tt = l4; l4 = l5; l5 = tt; }
                    if (l4 < l3) { auto tt = l3; l3 = l4; l4 = tt; }
                    if (l3 < l2) { auto tt = l2; l2 = l3; l3 = tt; }
                    if (l2 < l1) { auto tt = l1; l1 = l2; l2 = tt; }
                    if (l1 < l0) { auto tt = l0; l0 = l1; l1 = tt; }
                }
            }
            int nb[6] = { (int)(unsigned)l1, (int)(unsigned)l2, (int)(unsigned)l3,
                          (int)(unsigned)l4, (int)(unsigned)l5, (int)(unsigned)l6 };
            float s = 0.0f;
            #pragma unroll
            for (int k = 0; k < 6; ++k) {
                const int j = nb[k];
                #pragma unroll
                for (int bb = 0; bb < Bb; ++bb) {
                    const float* dn = disp + ((long)bb * Nn + q) * 3;
                    const float* dj = disp + ((long)bb * Nn + j) * 3;
                    const float ddx = dj[0] - dn[0];
                    const float ddy = dj[1] - dn[1];
                    const float ddz = dj[2] - dn[2];
                    s += ddx * ddx + ddy * ddy + ddz * ddz;
                }
            }
            sm.knn.part[tid] = s;
        }
        __syncthreads();
        if (tid == 0) {
            float tot = 0.0f;
            #pragma unroll
            for (int i = 0; i < 16; ++i) tot += sm.knn.part[i];
            atomicAdd(&acc[3], tot);
        }
    }
}

// ---- fused tail: reductions + last-block finalize ----
__global__ __launch_bounds__(256) void tail_reduce_kernel(
    const float* __restrict__ minArr, const float* __restrict__ pm,
    const float* __restrict__ tm, const float* __restrict__ dp,
    float* __restrict__ acc, float* __restrict__ out) {
    const int tid = threadIdx.x;
    const int stride = gridDim.x * blockDim.x;
    float sc = 0.0f, sm = 0.0f, sd = 0.0f;
    for (int i = blockIdx.x * blockDim.x + tid; i < 2 * Bb * Nn; i += stride) {
        sc += sqrtf(fmaxf(minArr[i], 1e-12f));
    }
    for (int i = blockIdx.x * blockDim.x + tid; i < Bb * Nn * 4; i += stride) {
        float d = pm[i] - tm[i];
        sm += d * d;
    }
    for (int i = blockIdx.x * blockDim.x + tid; i < Bb * Nn * 3; i += stride) {
        float v = dp[i];
        sd += v * v;
    }
    __shared__ float r0[256], r1[256], r2[256];
    r0[tid] = sc; r1[tid] = sm; r2[tid] = sd;
    __syncthreads();
    for (int w = 128; w > 0; w >>= 1) {
        if (tid < w) { r0[tid] += r0[tid + w]; r1[tid] += r1[tid + w]; r2[tid] += r2[tid + w]; }
        __syncthreads();
    }
    if (tid == 0) {
        atomicAdd(&acc[0], r0[0]);
        atomicAdd(&acc[1], r1[0]);
        atomicAdd(&acc[2], r2[0]);
        __threadfence();
        const unsigned done = atomicAdd((unsigned*)&acc[7], 1u);
        if (done == (unsigned)(gridDim.x - 1)) {
            const float c0 = atomicAdd(&acc[0], 0.0f);
            const float c1 = atomicAdd(&acc[1], 0.0f);
            const float c2 = atomicAdd(&acc[2], 0.0f);
            const float c3 = atomicAdd(&acc[3], 0.0f);
            const float cd  = c0 / (2.0f * Bb * Nn);
            const float mat = c1 / (float)(Bb * Nn * 4);
            const float dr  = c2 / (float)(Bb * Nn * 3);
            const float smo = c3 / (float)(Bb * Nn * KNB * 3);
            out[0] = 1.0f * cd + 0.1f * mat + 0.01f * dr + 0.005f * smo;
        }
    }
}

}  // namespace

extern "C" void kernel_launch(void* const* d_in, const int* in_sizes, int n_in,
                              void* d_out, int out_size, void* d_ws, size_t ws_size,
                              hipStream_t stream) {
    const float* pred_disp  = (const float*)d_in[0];
    const float* pred_mat   = (const float*)d_in[1];
    const float* target_pos = (const float*)d_in[2];
    const float* target_mat = (const float*)d_in[3];
    const float* tmpl       = (const float*)d_in[4];

    float* ws = (float*)d_ws;
    float* minArr = ws;                       // 2*B*N mins (exactly-once stores)
    float* acc = ws + 2 * Bb * Nn;            // 8 accumulators (acc[7] = block counter)

    init_ws_kernel<<<1, 64, 0, stream>>>(acc);

    fat_kernel<<<KNN_BLOCKS + CHB, 256, 0, stream>>>(
        pred_disp, tmpl, target_pos, minArr, acc);

    tail_reduce_kernel<<<TAIL_BLOCKS, 256, 0, stream>>>(
        minArr, pred_mat, target_mat, pred_disp, acc, (float*)d_out);
}

// Round 11
// 71.924 us; speedup vs baseline: 2.2025x; 1.2434x over previous
//
#include <hip/hip_runtime.h>

namespace {

typedef _Float16 half8 __attribute__((ext_vector_type(8)));
typedef float f32x16 __attribute__((ext_vector_type(16)));

constexpr int Bb = 4, Nn = 8192, KNB = 6;
constexpr int KSLAB = 1024;                  // knn slab points (16 KB)
constexpr int KCAP = 64;                     // knn candidate slots per query
constexpr int KNN_BLOCKS = Nn / 16;          // 512
constexpr int CH_BLOCKS = 512;               // 8 bd * 2 point-halves * 32 qb
constexpr int CH_CHUNK = 1024;               // points per staged chunk
constexpr int TAIL_BLOCKS = 128;

union SMemU {
    half8 aF[CH_CHUNK];                      // 16 KB: one frag per point (kg1 dropped: zero-B lanes)
    struct {
        float4 sp4[KSLAB];                   // 16 KB
        unsigned long long cand[16][KCAP];   // 8 KB
        int cnt[16];
        float part[16];
    } knn;                                   // ~24.7 KB
};

__device__ inline unsigned ordkey(float f) {
    unsigned b = __float_as_uint(f);
    return b ^ (unsigned)(((int)b >> 31) | 0x80000000);
}

__device__ inline half8 zero8() {
    half8 v;
    #pragma unroll
    for (int i = 0; i < 8; ++i) v[i] = (_Float16)0;
    return v;
}

// Consistent single-f16 scheme (kg0 slots only; kg1 lanes zero on B side):
//   acc = -p̂·q̂ + |p̂|²/2  (p̂,q̂ = f16-rounded coords; products exact in f32)
//   d2  = |q̂|² + 2·acc = |q̂-p̂|² ± ~7e-6  (clamped to >= 0)
__device__ inline half8 a_frag(float x, float y, float z) {
    _Float16 hx = (_Float16)x, hy = (_Float16)y, hz = (_Float16)z;
    const float xr = (float)hx, yr = (float)hy, zr = (float)hz;
    const float pp5 = 0.5f * (xr * xr + yr * yr + zr * zr);
    _Float16 ph = (_Float16)pp5, pl = (_Float16)(pp5 - (float)ph);
    half8 v;
    v[0] = -hx; v[1] = -hy; v[2] = -hz; v[3] = ph; v[4] = pl;
    v[5] = (_Float16)0; v[6] = (_Float16)0; v[7] = (_Float16)0;
    return v;
}
__device__ inline half8 b_frag(float x, float y, float z) {
    _Float16 hx = (_Float16)x, hy = (_Float16)y, hz = (_Float16)z;
    half8 v;
    v[0] = hx; v[1] = hy; v[2] = hz; v[3] = (_Float16)1; v[4] = (_Float16)1;
    v[5] = (_Float16)0; v[6] = (_Float16)0; v[7] = (_Float16)0;
    return v;
}

// ---------------- init: mins -> +inf, accumulators -> 0 ----------------
__global__ void init_ws_kernel(unsigned* __restrict__ minArr, float* __restrict__ acc) {
    int i = blockIdx.x * blockDim.x + threadIdx.x;
    if (i < 2 * Bb * Nn) minArr[i] = 0x7f800000u;
    if (i < 8) acc[i] = 0.0f;
}

// ---------------- fat kernel: knn blocks [0,512) + chamfer-mfma blocks [512,1024) ----
__global__ __launch_bounds__(256, 4) void fat_kernel(
    const float* __restrict__ disp, const float* __restrict__ tmpl,
    const float* __restrict__ targ, unsigned* __restrict__ outMin,
    float* __restrict__ acc) {
    __shared__ SMemU sm;
    const int tid = threadIdx.x;

    if (blockIdx.x >= KNN_BLOCKS) {
        // ================= chamfer via MFMA, half the points per block =================
        const int cb = (int)blockIdx.x - KNN_BLOCKS;   // 0..511
        const int qb = (cb & 31) * 256;
        const int half_ = (cb >> 5) & 1;
        const int bd = cb >> 6;                        // 0..7
        const int dir = bd & 1, b = bd >> 1;
        const int lane = tid & 63, w = tid >> 6;
        const int l31 = lane & 31, kg = lane >> 5;

        float qq[2];
        half8 Bf[2];
        #pragma unroll
        for (int j = 0; j < 2; ++j) {
            const int q = qb + w * 64 + j * 32 + l31;
            const long e = ((long)b * Nn + q) * 3;
            float x, y, z;
            if (dir == 0) {   // queries = pred
                x = tmpl[e] + disp[e]; y = tmpl[e+1] + disp[e+1]; z = tmpl[e+2] + disp[e+2];
            } else {          // queries = targ
                x = targ[e]; y = targ[e+1]; z = targ[e+2];
            }
            _Float16 hx = (_Float16)x, hy = (_Float16)y, hz = (_Float16)z;
            const float xr = (float)hx, yr = (float)hy, zr = (float)hz;
            qq[j] = xr * xr + yr * yr + zr * zr;
            Bf[j] = (kg == 0) ? b_frag(x, y, z) : zero8();
        }

        float run0 = 1e38f, run1 = 1e38f;
        const f32x16 zc = {0.f, 0.f, 0.f, 0.f, 0.f, 0.f, 0.f, 0.f,
                           0.f, 0.f, 0.f, 0.f, 0.f, 0.f, 0.f, 0.f};

        for (int ch = 0; ch < 4; ++ch) {
            const int pbase = half_ * 4096 + ch * CH_CHUNK;
            __syncthreads();
            {
                // stage 1024 points; thread stages 4 consecutive points via 3x float4
                const long fbase = ((long)b * Nn + pbase) * 3;   // /4-aligned (pbase%1024==0)
                const float4* s4 = (const float4*)((dir == 0 ? targ : tmpl) + fbase);
                float4 t0 = s4[tid * 3 + 0], t1 = s4[tid * 3 + 1], t2 = s4[tid * 3 + 2];
                if (dir == 1) {   // points = pred = tmpl + disp
                    const float4* d4 = (const float4*)(disp + fbase);
                    float4 u0 = d4[tid * 3 + 0], u1 = d4[tid * 3 + 1], u2 = d4[tid * 3 + 2];
                    t0.x += u0.x; t0.y += u0.y; t0.z += u0.z; t0.w += u0.w;
                    t1.x += u1.x; t1.y += u1.y; t1.z += u1.z; t1.w += u1.w;
                    t2.x += u2.x; t2.y += u2.y; t2.z += u2.z; t2.w += u2.w;
                }
                const int b4 = tid * 4;
                sm.aF[b4 + 0] = a_frag(t0.x, t0.y, t0.z);
                sm.aF[b4 + 1] = a_frag(t0.w, t1.x, t1.y);
                sm.aF[b4 + 2] = a_frag(t1.z, t1.w, t2.x);
                sm.aF[b4 + 3] = a_frag(t2.y, t2.z, t2.w);
            }
            __syncthreads();
            #pragma unroll 8
            for (int tt = 0; tt < 32; ++tt) {
                const half8 a = sm.aF[tt * 32 + l31];   // lanes l,l+32 broadcast (x0 on kg1)
                f32x16 c0 = __builtin_amdgcn_mfma_f32_32x32x16_f16(a, Bf[0], zc, 0, 0, 0);
                f32x16 c1 = __builtin_amdgcn_mfma_f32_32x32x16_f16(a, Bf[1], zc, 0, 0, 0);
                #pragma unroll
                for (int r = 0; r < 16; r += 2) {
                    run0 = fminf(run0, fminf(c0[r], c0[r + 1]));  // -> v_min3_f32
                    run1 = fminf(run1, fminf(c1[r], c1[r + 1]));
                }
            }
        }

        run0 = fminf(run0, __shfl_xor(run0, 32, 64));
        run1 = fminf(run1, __shfl_xor(run1, 32, 64));
        if (lane < 32) {
            const long base = ((long)dir * Bb + b) * Nn;
            {
                const int q = qb + w * 64 + l31;
                const float d2 = fmaxf(fmaf(2.0f, run0, qq[0]), 0.0f);
                atomicMin(&outMin[base + q], __float_as_uint(d2));
            }
            {
                const int q = qb + w * 64 + 32 + l31;
                const float d2 = fmaxf(fmaf(2.0f, run1, qq[1]), 0.0f);
                atomicMin(&outMin[base + q], __float_as_uint(d2));
            }
        }
    } else {
        // ================= knn + smooth (verified structure; float4 staging) ==========
        const int kb = blockIdx.x;
        const int lane = tid & 63;
        const int wid = tid >> 6;
        const int c = lane;

        const int qbase = kb * 16 + wid * 4;
        float axq[4], ayq[4], azq[4];
        #pragma unroll
        for (int i = 0; i < 4; ++i) {
            axq[i] = -tmpl[(qbase + i) * 3 + 0];
            ayq[i] = -tmpl[(qbase + i) * 3 + 1];
            azq[i] = -tmpl[(qbase + i) * 3 + 2];
        }
        const float INFf = __uint_as_float(0x7f800000u);

        if (tid < 16) sm.knn.cnt[tid] = 0;

        float cm[4];
        #pragma unroll
        for (int i = 0; i < 4; ++i) cm[i] = INFf;

        const float4* t4 = (const float4*)tmpl;   // template[0]

        for (int slab = 0; slab < Nn / KSLAB; ++slab) {
            __syncthreads();
            {
                float4 t0 = t4[768 * slab + tid * 3 + 0];
                float4 t1 = t4[768 * slab + tid * 3 + 1];
                float4 t2 = t4[768 * slab + tid * 3 + 2];
                const int b4 = tid * 4;
                sm.knn.sp4[b4 + 0] = make_float4(t0.x, t0.y, t0.z,
                    0.5f * (t0.x * t0.x + t0.y * t0.y + t0.z * t0.z));
                sm.knn.sp4[b4 + 1] = make_float4(t0.w, t1.x, t1.y,
                    0.5f * (t0.w * t0.w + t1.x * t1.x + t1.y * t1.y));
                sm.knn.sp4[b4 + 2] = make_float4(t1.z, t1.w, t2.x,
                    0.5f * (t1.z * t1.z + t1.w * t1.w + t2.x * t2.x));
                sm.knn.sp4[b4 + 3] = make_float4(t2.y, t2.z, t2.w,
                    0.5f * (t2.y * t2.y + t2.z * t2.z + t2.w * t2.w));
            }
            __syncthreads();
            #pragma unroll 2
            for (int jj = 0; jj < KSLAB / 64; jj += 2) {
                const float4 P0 = sm.knn.sp4[(jj + 0) * 64 + c];
                const float4 P1 = sm.knn.sp4[(jj + 1) * 64 + c];
                #pragma unroll
                for (int i = 0; i < 4; ++i) {
                    const float s0 = fmaf(P0.x, axq[i], fmaf(P0.y, ayq[i], fmaf(P0.z, azq[i], P0.w)));
                    const float s1 = fmaf(P1.x, axq[i], fmaf(P1.y, ayq[i], fmaf(P1.z, azq[i], P1.w)));
                    cm[i] = fminf(fminf(cm[i], s0), s1);
                }
            }
        }

        float T[4];
        #pragma unroll
        for (int i = 0; i < 4; ++i) {
            float v = cm[i], h;
            #pragma unroll
            for (int t = 0; t < 7; ++t) {
                h = v;
                h = fminf(h, __shfl_xor(h, 32, 64));
                h = fminf(h, __shfl_xor(h, 16, 64));
                h = fminf(h, __shfl_xor(h, 8, 64));
                h = fminf(h, __shfl_xor(h, 4, 64));
                h = fminf(h, __shfl_xor(h, 2, 64));
                h = fminf(h, __shfl_xor(h, 1, 64));
                T[i] = h;
                if (v == h) v = INFf;   // >=7 chunks knocked out => >=7 pts <= T
            }
        }

        for (int slab = 0; slab < Nn / KSLAB; ++slab) {
            __syncthreads();
            {
                float4 t0 = t4[768 * slab + tid * 3 + 0];
                float4 t1 = t4[768 * slab + tid * 3 + 1];
                float4 t2 = t4[768 * slab + tid * 3 + 2];
                const int b4 = tid * 4;
                sm.knn.sp4[b4 + 0] = make_float4(t0.x, t0.y, t0.z,
                    0.5f * (t0.x * t0.x + t0.y * t0.y + t0.z * t0.z));
                sm.knn.sp4[b4 + 1] = make_float4(t0.w, t1.x, t1.y,
                    0.5f * (t0.w * t0.w + t1.x * t1.x + t1.y * t1.y));
                sm.knn.sp4[b4 + 2] = make_float4(t1.z, t1.w, t2.x,
                    0.5f * (t1.z * t1.z + t1.w * t1.w + t2.x * t2.x));
                sm.knn.sp4[b4 + 3] = make_float4(t2.y, t2.z, t2.w,
                    0.5f * (t2.y * t2.y + t2.z * t2.z + t2.w * t2.w));
            }
            __syncthreads();
            #pragma unroll 2
            for (int jj = 0; jj < KSLAB / 64; ++jj) {
                const float4 P = sm.knn.sp4[jj * 64 + c];
                const int p = slab * KSLAB + jj * 64 + c;
                #pragma unroll
                for (int i = 0; i < 4; ++i) {
                    const float s = fmaf(P.x, axq[i], fmaf(P.y, ayq[i], fmaf(P.z, azq[i], P.w)));
                    if (s <= T[i]) {
                        const int slot = wid * 4 + i;
                        const int pos = atomicAdd(&sm.knn.cnt[slot], 1);
                        if (pos < KCAP)
                            sm.knn.cand[slot][pos] =
                                ((unsigned long long)ordkey(s) << 32) | (unsigned)p;
                    }
                }
            }
        }
        __syncthreads();

        if (tid < 16) {
            const int q = kb * 16 + tid;
            const int m = min(sm.knn.cnt[tid], KCAP);
            unsigned long long l0 = ~0ULL, l1 = ~0ULL, l2 = ~0ULL, l3 = ~0ULL,
                               l4 = ~0ULL, l5 = ~0ULL, l6 = ~0ULL;
            for (int t = 0; t < m; ++t) {
                const unsigned long long key = sm.knn.cand[tid][t];
                if (key < l6) {
                    l6 = key;
                    if (l6 < l5) { auto tt = l5; l5 = l6; l6 = tt; }
                    if (l5 < l4) { auto tt = l4; l4 = l5; l5 = tt; }
                    if (l4 < l3) { auto tt = l3; l3 = l4; l4 = tt; }
                    if (l3 < l2) { auto tt = l2; l2 = l3; l3 = tt; }
                    if (l2 < l1) { auto tt = l1; l1 = l2; l2 = tt; }
                    if (l1 < l0) { auto tt = l0; l0 = l1; l1 = tt; }
                }
            }
            int nb[6] = { (int)(unsigned)l1, (int)(unsigned)l2, (int)(unsigned)l3,
                          (int)(unsigned)l4, (int)(unsigned)l5, (int)(unsigned)l6 };
            float s = 0.0f;
            #pragma unroll
            for (int k = 0; k < 6; ++k) {
                const int j = nb[k];
                #pragma unroll
                for (int bb = 0; bb < Bb; ++bb) {
                    const float* dn = disp + ((long)bb * Nn + q) * 3;
                    const float* dj = disp + ((long)bb * Nn + j) * 3;
                    const float ddx = dj[0] - dn[0];
                    const float ddy = dj[1] - dn[1];
                    const float ddz = dj[2] - dn[2];
                    s += ddx * ddx + ddy * ddy + ddz * ddz;
                }
            }
            sm.knn.part[tid] = s;
        }
        __syncthreads();
        if (tid == 0) {
            float tot = 0.0f;
            #pragma unroll
            for (int i = 0; i < 16; ++i) tot += sm.knn.part[i];
            atomicAdd(&acc[3], tot);
        }
    }
}

// ---- fused tail: reductions + last-block finalize ----
__global__ __launch_bounds__(256) void tail_reduce_kernel(
    const float* __restrict__ minArr, const float* __restrict__ pm,
    const float* __restrict__ tm, const float* __restrict__ dp,
    float* __restrict__ acc, float* __restrict__ out) {
    const int tid = threadIdx.x;
    const int stride = gridDim.x * blockDim.x;
    float sc = 0.0f, sm = 0.0f, sd = 0.0f;
    for (int i = blockIdx.x * blockDim.x + tid; i < 2 * Bb * Nn; i += stride) {
        sc += sqrtf(fmaxf(minArr[i], 1e-12f));
    }
    for (int i = blockIdx.x * blockDim.x + tid; i < Bb * Nn * 4; i += stride) {
        float d = pm[i] - tm[i];
        sm += d * d;
    }
    for (int i = blockIdx.x * blockDim.x + tid; i < Bb * Nn * 3; i += stride) {
        float v = dp[i];
        sd += v * v;
    }
    __shared__ float r0[256], r1[256], r2[256];
    r0[tid] = sc; r1[tid] = sm; r2[tid] = sd;
    __syncthreads();
    for (int w = 128; w > 0; w >>= 1) {
        if (tid < w) { r0[tid] += r0[tid + w]; r1[tid] += r1[tid + w]; r2[tid] += r2[tid + w]; }
        __syncthreads();
    }
    if (tid == 0) {
        atomicAdd(&acc[0], r0[0]);
        atomicAdd(&acc[1], r1[0]);
        atomicAdd(&acc[2], r2[0]);
        __threadfence();
        const unsigned done = atomicAdd((unsigned*)&acc[7], 1u);
        if (done == (unsigned)(gridDim.x - 1)) {
            const float c0 = atomicAdd(&acc[0], 0.0f);
            const float c1 = atomicAdd(&acc[1], 0.0f);
            const float c2 = atomicAdd(&acc[2], 0.0f);
            const float c3 = atomicAdd(&acc[3], 0.0f);
            const float cd  = c0 / (2.0f * Bb * Nn);
            const float mat = c1 / (float)(Bb * Nn * 4);
            const float dr  = c2 / (float)(Bb * Nn * 3);
            const float smo = c3 / (float)(Bb * Nn * KNB * 3);
            out[0] = 1.0f * cd + 0.1f * mat + 0.01f * dr + 0.005f * smo;
        }
    }
}

}  // namespace

extern "C" void kernel_launch(void* const* d_in, const int* in_sizes, int n_in,
                              void* d_out, int out_size, void* d_ws, size_t ws_size,
                              hipStream_t stream) {
    const float* pred_disp  = (const float*)d_in[0];
    const float* pred_mat   = (const float*)d_in[1];
    const float* target_pos = (const float*)d_in[2];
    const float* target_mat = (const float*)d_in[3];
    const float* tmpl       = (const float*)d_in[4];

    float* ws = (float*)d_ws;
    unsigned* minArr = (unsigned*)ws;         // 2*B*N mins (atomicMin merge of 2 halves)
    float* acc = ws + 2 * Bb * Nn;            // 8 accumulators (acc[7] = block counter)

    init_ws_kernel<<<(2 * Bb * Nn) / 256, 256, 0, stream>>>(minArr, acc);

    fat_kernel<<<KNN_BLOCKS + CH_BLOCKS, 256, 0, stream>>>(
        pred_disp, tmpl, target_pos, minArr, acc);

    tail_reduce_kernel<<<TAIL_BLOCKS, 256, 0, stream>>>(
        (const float*)minArr, pred_mat, target_mat, pred_disp, acc, (float*)d_out);
}

// Round 12
// 70.414 us; speedup vs baseline: 2.2497x; 1.0214x over previous
//
#include <hip/hip_runtime.h>

namespace {

typedef _Float16 half8 __attribute__((ext_vector_type(8)));
typedef float f32x16 __attribute__((ext_vector_type(16)));

constexpr int Bb = 4, Nn = 8192, KNB = 6;
constexpr int KSLAB = 1024;                  // knn slab points (16 KB)
constexpr int KCAP = 64;                     // knn candidate slots per query
constexpr int KNN_BLOCKS = Nn / 16;          // 512
constexpr int CH_BLOCKS = 512;               // 8 bd * 2 point-halves * 32 qb
constexpr int CH_CHUNK = 1024;               // points per staged chunk
constexpr int TAIL_BLOCKS = 128;

// transposed slab slot: point p (0..1023) -> slot; writes AND reads conflict-free
#define TSLOT(p) ((((p) & 3) << 8) | ((p) >> 2))

union SMemU {
    half8 aF[CH_CHUNK];                      // 16 KB chamfer frags (transposed layout)
    struct {
        float4 sp4[KSLAB];                   // 16 KB (transposed layout)
        unsigned long long cand[16][KCAP];   // 8 KB
        int cnt[16];
        float part[16];
    } knn;                                   // ~24.7 KB
};

__device__ inline unsigned ordkey(float f) {
    unsigned b = __float_as_uint(f);
    return b ^ (unsigned)(((int)b >> 31) | 0x80000000);
}

__device__ inline half8 zero8() {
    half8 v;
    #pragma unroll
    for (int i = 0; i < 8; ++i) v[i] = (_Float16)0;
    return v;
}

// Consistent single-f16 scheme (kg0 slots only; kg1 lanes zero on B side):
//   acc = -p̂·q̂ + |p̂|²/2 ; d2 = |q̂|² + 2·acc = |q̂-p̂|² ± ~7e-6 (clamped >= 0)
__device__ inline half8 a_frag(float x, float y, float z) {
    _Float16 hx = (_Float16)x, hy = (_Float16)y, hz = (_Float16)z;
    const float xr = (float)hx, yr = (float)hy, zr = (float)hz;
    const float pp5 = 0.5f * (xr * xr + yr * yr + zr * zr);
    _Float16 ph = (_Float16)pp5, pl = (_Float16)(pp5 - (float)ph);
    half8 v;
    v[0] = -hx; v[1] = -hy; v[2] = -hz; v[3] = ph; v[4] = pl;
    v[5] = (_Float16)0; v[6] = (_Float16)0; v[7] = (_Float16)0;
    return v;
}
__device__ inline half8 b_frag(float x, float y, float z) {
    _Float16 hx = (_Float16)x, hy = (_Float16)y, hz = (_Float16)z;
    half8 v;
    v[0] = hx; v[1] = hy; v[2] = hz; v[3] = (_Float16)1; v[4] = (_Float16)1;
    v[5] = (_Float16)0; v[6] = (_Float16)0; v[7] = (_Float16)0;
    return v;
}

// ---------------- init: mins -> +inf, accumulators -> 0 ----------------
__global__ void init_ws_kernel(unsigned* __restrict__ minArr, float* __restrict__ acc) {
    int i = blockIdx.x * blockDim.x + threadIdx.x;
    if (i < 2 * Bb * Nn) minArr[i] = 0x7f800000u;
    if (i < 8) acc[i] = 0.0f;
}

// ---------------- fat kernel: knn blocks [0,512) + chamfer-mfma blocks [512,1024) ----
__global__ __launch_bounds__(256, 4) void fat_kernel(
    const float* __restrict__ disp, const float* __restrict__ tmpl,
    const float* __restrict__ targ, unsigned* __restrict__ outMin,
    float* __restrict__ acc) {
    __shared__ SMemU sm;
    const int tid = threadIdx.x;

    if (blockIdx.x >= KNN_BLOCKS) {
        // ================= chamfer via MFMA, half the points per block =================
        const int cb = (int)blockIdx.x - KNN_BLOCKS;   // 0..511
        const int qb = (cb & 31) * 256;
        const int half_ = (cb >> 5) & 1;
        const int bd = cb >> 6;                        // 0..7
        const int dir = bd & 1, b = bd >> 1;
        const int lane = tid & 63, w = tid >> 6;
        const int l31 = lane & 31, kg = lane >> 5;
        const int rbase = ((l31 & 3) << 8) | (l31 >> 2);   // TSLOT lane base (+8 per tile)

        float qq[2];
        half8 Bf[2];
        #pragma unroll
        for (int j = 0; j < 2; ++j) {
            const int q = qb + w * 64 + j * 32 + l31;
            const long e = ((long)b * Nn + q) * 3;
            float x, y, z;
            if (dir == 0) {   // queries = pred
                x = tmpl[e] + disp[e]; y = tmpl[e+1] + disp[e+1]; z = tmpl[e+2] + disp[e+2];
            } else {          // queries = targ
                x = targ[e]; y = targ[e+1]; z = targ[e+2];
            }
            _Float16 hx = (_Float16)x, hy = (_Float16)y, hz = (_Float16)z;
            const float xr = (float)hx, yr = (float)hy, zr = (float)hz;
            qq[j] = xr * xr + yr * yr + zr * zr;
            Bf[j] = (kg == 0) ? b_frag(x, y, z) : zero8();
        }

        float run0 = 1e38f, run1 = 1e38f;
        const f32x16 zc = {0.f, 0.f, 0.f, 0.f, 0.f, 0.f, 0.f, 0.f,
                           0.f, 0.f, 0.f, 0.f, 0.f, 0.f, 0.f, 0.f};

        for (int ch = 0; ch < 4; ++ch) {
            const int pbase = half_ * 4096 + ch * CH_CHUNK;
            __syncthreads();
            {
                // thread stages 4 consecutive points via 3x float4; transposed LDS write
                const long fbase = ((long)b * Nn + pbase) * 3;   // float4-aligned
                const float4* s4 = (const float4*)((dir == 0 ? targ : tmpl) + fbase);
                float4 t0 = s4[tid * 3 + 0], t1 = s4[tid * 3 + 1], t2 = s4[tid * 3 + 2];
                if (dir == 1) {   // points = pred = tmpl + disp
                    const float4* d4 = (const float4*)(disp + fbase);
                    float4 u0 = d4[tid * 3 + 0], u1 = d4[tid * 3 + 1], u2 = d4[tid * 3 + 2];
                    t0.x += u0.x; t0.y += u0.y; t0.z += u0.z; t0.w += u0.w;
                    t1.x += u1.x; t1.y += u1.y; t1.z += u1.z; t1.w += u1.w;
                    t2.x += u2.x; t2.y += u2.y; t2.z += u2.z; t2.w += u2.w;
                }
                sm.aF[0 * 256 + tid] = a_frag(t0.x, t0.y, t0.z);   // point 4t+0
                sm.aF[1 * 256 + tid] = a_frag(t0.w, t1.x, t1.y);   // point 4t+1
                sm.aF[2 * 256 + tid] = a_frag(t1.z, t1.w, t2.x);   // point 4t+2
                sm.aF[3 * 256 + tid] = a_frag(t2.y, t2.z, t2.w);   // point 4t+3
            }
            __syncthreads();
            #pragma unroll 8
            for (int tt = 0; tt < 32; ++tt) {
                const half8 a = sm.aF[rbase + tt * 8];   // point tt*32+l31, transposed
                f32x16 c0 = __builtin_amdgcn_mfma_f32_32x32x16_f16(a, Bf[0], zc, 0, 0, 0);
                f32x16 c1 = __builtin_amdgcn_mfma_f32_32x32x16_f16(a, Bf[1], zc, 0, 0, 0);
                #pragma unroll
                for (int r = 0; r < 16; r += 2) {
                    run0 = fminf(run0, fminf(c0[r], c0[r + 1]));  // -> v_min3_f32
                    run1 = fminf(run1, fminf(c1[r], c1[r + 1]));
                }
            }
        }

        run0 = fminf(run0, __shfl_xor(run0, 32, 64));
        run1 = fminf(run1, __shfl_xor(run1, 32, 64));
        if (lane < 32) {
            const long base = ((long)dir * Bb + b) * Nn;
            {
                const int q = qb + w * 64 + l31;
                const float d2 = fmaxf(fmaf(2.0f, run0, qq[0]), 0.0f);
                atomicMin(&outMin[base + q], __float_as_uint(d2));
            }
            {
                const int q = qb + w * 64 + 32 + l31;
                const float d2 = fmaxf(fmaf(2.0f, run1, qq[1]), 0.0f);
                atomicMin(&outMin[base + q], __float_as_uint(d2));
            }
        }
    } else {
        // ================= knn + smooth (transposed staging) =================
        const int kb = blockIdx.x;
        const int lane = tid & 63;
        const int wid = tid >> 6;
        const int c = lane;
        const int rb = ((c & 3) << 8) | (c >> 2);   // TSLOT lane base (+16 per jj)

        const int qbase = kb * 16 + wid * 4;
        float axq[4], ayq[4], azq[4];
        #pragma unroll
        for (int i = 0; i < 4; ++i) {
            axq[i] = -tmpl[(qbase + i) * 3 + 0];
            ayq[i] = -tmpl[(qbase + i) * 3 + 1];
            azq[i] = -tmpl[(qbase + i) * 3 + 2];
        }
        const float INFf = __uint_as_float(0x7f800000u);

        if (tid < 16) sm.knn.cnt[tid] = 0;

        float cm[4];
        #pragma unroll
        for (int i = 0; i < 4; ++i) cm[i] = INFf;

        const float4* t4 = (const float4*)tmpl;   // template[0]

        for (int slab = 0; slab < Nn / KSLAB; ++slab) {
            __syncthreads();
            {
                float4 t0 = t4[768 * slab + tid * 3 + 0];
                float4 t1 = t4[768 * slab + tid * 3 + 1];
                float4 t2 = t4[768 * slab + tid * 3 + 2];
                sm.knn.sp4[0 * 256 + tid] = make_float4(t0.x, t0.y, t0.z,
                    0.5f * (t0.x * t0.x + t0.y * t0.y + t0.z * t0.z));
                sm.knn.sp4[1 * 256 + tid] = make_float4(t0.w, t1.x, t1.y,
                    0.5f * (t0.w * t0.w + t1.x * t1.x + t1.y * t1.y));
                sm.knn.sp4[2 * 256 + tid] = make_float4(t1.z, t1.w, t2.x,
                    0.5f * (t1.z * t1.z + t1.w * t1.w + t2.x * t2.x));
                sm.knn.sp4[3 * 256 + tid] = make_float4(t2.y, t2.z, t2.w,
                    0.5f * (t2.y * t2.y + t2.z * t2.z + t2.w * t2.w));
            }
            __syncthreads();
            #pragma unroll 2
            for (int jj = 0; jj < KSLAB / 64; jj += 2) {
                const float4 P0 = sm.knn.sp4[rb + (jj + 0) * 16];
                const float4 P1 = sm.knn.sp4[rb + (jj + 1) * 16];
                #pragma unroll
                for (int i = 0; i < 4; ++i) {
                    const float s0 = fmaf(P0.x, axq[i], fmaf(P0.y, ayq[i], fmaf(P0.z, azq[i], P0.w)));
                    const float s1 = fmaf(P1.x, axq[i], fmaf(P1.y, ayq[i], fmaf(P1.z, azq[i], P1.w)));
                    cm[i] = fminf(fminf(cm[i], s0), s1);
                }
            }
        }

        float T[4];
        #pragma unroll
        for (int i = 0; i < 4; ++i) {
            float v = cm[i], h;
            #pragma unroll
            for (int t = 0; t < 7; ++t) {
                h = v;
                h = fminf(h, __shfl_xor(h, 32, 64));
                h = fminf(h, __shfl_xor(h, 16, 64));
                h = fminf(h, __shfl_xor(h, 8, 64));
                h = fminf(h, __shfl_xor(h, 4, 64));
                h = fminf(h, __shfl_xor(h, 2, 64));
                h = fminf(h, __shfl_xor(h, 1, 64));
                T[i] = h;
                if (v == h) v = INFf;   // >=7 chunks knocked out => >=7 pts <= T
            }
        }

        for (int slab = 0; slab < Nn / KSLAB; ++slab) {
            __syncthreads();
            {
                float4 t0 = t4[768 * slab + tid * 3 + 0];
                float4 t1 = t4[768 * slab + tid * 3 + 1];
                float4 t2 = t4[768 * slab + tid * 3 + 2];
                sm.knn.sp4[0 * 256 + tid] = make_float4(t0.x, t0.y, t0.z,
                    0.5f * (t0.x * t0.x + t0.y * t0.y + t0.z * t0.z));
                sm.knn.sp4[1 * 256 + tid] = make_float4(t0.w, t1.x, t1.y,
                    0.5f * (t0.w * t0.w + t1.x * t1.x + t1.y * t1.y));
                sm.knn.sp4[2 * 256 + tid] = make_float4(t1.z, t1.w, t2.x,
                    0.5f * (t1.z * t1.z + t1.w * t1.w + t2.x * t2.x));
                sm.knn.sp4[3 * 256 + tid] = make_float4(t2.y, t2.z, t2.w,
                    0.5f * (t2.y * t2.y + t2.z * t2.z + t2.w * t2.w));
            }
            __syncthreads();
            #pragma unroll 2
            for (int jj = 0; jj < KSLAB / 64; ++jj) {
                const float4 P = sm.knn.sp4[rb + jj * 16];
                const int p = slab * KSLAB + jj * 64 + c;
                #pragma unroll
                for (int i = 0; i < 4; ++i) {
                    const float s = fmaf(P.x, axq[i], fmaf(P.y, ayq[i], fmaf(P.z, azq[i], P.w)));
                    if (s <= T[i]) {
                        const int slot = wid * 4 + i;
                        const int pos = atomicAdd(&sm.knn.cnt[slot], 1);
                        if (pos < KCAP)
                            sm.knn.cand[slot][pos] =
                                ((unsigned long long)ordkey(s) << 32) | (unsigned)p;
                    }
                }
            }
        }
        __syncthreads();

        if (tid < 16) {
            const int q = kb * 16 + tid;
            const int m = min(sm.knn.cnt[tid], KCAP);
            unsigned long long l0 = ~0ULL, l1 = ~0ULL, l2 = ~0ULL, l3 = ~0ULL,
                               l4 = ~0ULL, l5 = ~0ULL, l6 = ~0ULL;
            for (int t = 0; t < m; ++t) {
                const unsigned long long key = sm.knn.cand[tid][t];
                if (key < l6) {
                    l6 = key;
                    if (l6 < l5) { auto tt = l5; l5 = l6; l6 = tt; }
                    if (l5 < l4) { auto tt = l4; l4 = l5; l5 = tt; }
                    if (l4 < l3) { auto tt = l3; l3 = l4; l4 = tt; }
                    if (l3 < l2) { auto tt = l2; l2 = l3; l3 = tt; }
                    if (l2 < l1) { auto tt = l1; l1 = l2; l2 = tt; }
                    if (l1 < l0) { auto tt = l0; l0 = l1; l1 = tt; }
                }
            }
            int nb[6] = { (int)(unsigned)l1, (int)(unsigned)l2, (int)(unsigned)l3,
                          (int)(unsigned)l4, (int)(unsigned)l5, (int)(unsigned)l6 };
            float s = 0.0f;
            #pragma unroll
            for (int k = 0; k < 6; ++k) {
                const int j = nb[k];
                #pragma unroll
                for (int bb = 0; bb < Bb; ++bb) {
                    const float* dn = disp + ((long)bb * Nn + q) * 3;
                    const float* dj = disp + ((long)bb * Nn + j) * 3;
                    const float ddx = dj[0] - dn[0];
                    const float ddy = dj[1] - dn[1];
                    const float ddz = dj[2] - dn[2];
                    s += ddx * ddx + ddy * ddy + ddz * ddz;
                }
            }
            sm.knn.part[tid] = s;
        }
        __syncthreads();
        if (tid == 0) {
            float tot = 0.0f;
            #pragma unroll
            for (int i = 0; i < 16; ++i) tot += sm.knn.part[i];
            atomicAdd(&acc[3], tot);
        }
    }
}

// ---- fused tail: reductions + last-block finalize ----
__global__ __launch_bounds__(256) void tail_reduce_kernel(
    const float* __restrict__ minArr, const float* __restrict__ pm,
    const float* __restrict__ tm, const float* __restrict__ dp,
    float* __restrict__ acc, float* __restrict__ out) {
    const int tid = threadIdx.x;
    const int stride = gridDim.x * blockDim.x;
    float sc = 0.0f, sm = 0.0f, sd = 0.0f;
    for (int i = blockIdx.x * blockDim.x + tid; i < 2 * Bb * Nn; i += stride) {
        sc += sqrtf(fmaxf(minArr[i], 1e-12f));
    }
    for (int i = blockIdx.x * blockDim.x + tid; i < Bb * Nn * 4; i += stride) {
        float d = pm[i] - tm[i];
        sm += d * d;
    }
    for (int i = blockIdx.x * blockDim.x + tid; i < Bb * Nn * 3; i += stride) {
        float v = dp[i];
        sd += v * v;
    }
    __shared__ float r0[256], r1[256], r2[256];
    r0[tid] = sc; r1[tid] = sm; r2[tid] = sd;
    __syncthreads();
    for (int w = 128; w > 0; w >>= 1) {
        if (tid < w) { r0[tid] += r0[tid + w]; r1[tid] += r1[tid + w]; r2[tid] += r2[tid + w]; }
        __syncthreads();
    }
    if (tid == 0) {
        atomicAdd(&acc[0], r0[0]);
        atomicAdd(&acc[1], r1[0]);
        atomicAdd(&acc[2], r2[0]);
        __threadfence();
        const unsigned done = atomicAdd((unsigned*)&acc[7], 1u);
        if (done == (unsigned)(gridDim.x - 1)) {
            const float c0 = atomicAdd(&acc[0], 0.0f);
            const float c1 = atomicAdd(&acc[1], 0.0f);
            const float c2 = atomicAdd(&acc[2], 0.0f);
            const float c3 = atomicAdd(&acc[3], 0.0f);
            const float cd  = c0 / (2.0f * Bb * Nn);
            const float mat = c1 / (float)(Bb * Nn * 4);
            const float dr  = c2 / (float)(Bb * Nn * 3);
            const float smo = c3 / (float)(Bb * Nn * KNB * 3);
            out[0] = 1.0f * cd + 0.1f * mat + 0.01f * dr + 0.005f * smo;
        }
    }
}

}  // namespace

extern "C" void kernel_launch(void* const* d_in, const int* in_sizes, int n_in,
                              void* d_out, int out_size, void* d_ws, size_t ws_size,
                              hipStream_t stream) {
    const float* pred_disp  = (const float*)d_in[0];
    const float* pred_mat   = (const float*)d_in[1];
    const float* target_pos = (const float*)d_in[2];
    const float* target_mat = (const float*)d_in[3];
    const float* tmpl       = (const float*)d_in[4];

    float* ws = (float*)d_ws;
    unsigned* minArr = (unsigned*)ws;         // 2*B*N mins (atomicMin merge of 2 halves)
    float* acc = ws + 2 * Bb * Nn;            // 8 accumulators (acc[7] = block counter)

    init_ws_kernel<<<(2 * Bb * Nn) / 256, 256, 0, stream>>>(minArr, acc);

    fat_kernel<<<KNN_BLOCKS + CH_BLOCKS, 256, 0, stream>>>(
        pred_disp, tmpl, target_pos, minArr, acc);

    tail_reduce_kernel<<<TAIL_BLOCKS, 256, 0, stream>>>(
        (const float*)minArr, pred_mat, target_mat, pred_disp, acc, (float*)d_out);
}